// Round 1
// baseline (1274.756 us; speedup 1.0000x reference)
//
#include <hip/hip_runtime.h>
#include <math.h>

#define NFB  512     // B = nf*ns
#define NMEM 30
#define PIX  1024    // 32*32
#define NGTHC 15
#define EPSF 1e-5f

// ---------------------------------------------------------------------------
// K0: build inp (B,14,32,32): mask weights, ptm per-memory max + masked stats,
// max_ts, per-pixel pmt masked stats.
// ---------------------------------------------------------------------------
__global__ __launch_bounds__(256) void k0_stats(
    const float* __restrict__ ts, const float* __restrict__ ptm,
    const float* __restrict__ pmt, const float* __restrict__ piou,
    const int* __restrict__ mask, float* __restrict__ inp)
{
  const int b = blockIdx.x;
  const int t = threadIdx.x;
  const int wave = t >> 6, lane = t & 63;
  __shared__ float s_mf[NMEM], s_gth[NMEM], s_oth[NMEM];
  __shared__ float s_pmax[NMEM];
  __shared__ float s_red[4];
  __shared__ float s_scal[7];  // max_ts, m_mm, s_mm, m_gm, s_gm, m_om, s_om
  __shared__ float s_cnt[3];   // cnt_m, cnt_g, cnt_o

  if (t == 0) {
    float cum = 0.f, cm = 0.f, cg = 0.f, co = 0.f;
    for (int m = 0; m < NMEM; ++m) {
      float f  = (mask[b * NMEM + m] != 0) ? 1.f : 0.f;
      // ref: rank = cumsum(mf)-1 ; for masked m rank == #trues before m
      float gg = (cum < (float)NGTHC) ? f : 0.f;
      float oo = f - gg;
      cum += f;
      s_mf[m] = f; s_gth[m] = gg; s_oth[m] = oo;
      cm += f; cg += gg; co += oo;
    }
    s_cnt[0] = cm; s_cnt[1] = cg; s_cnt[2] = co;
  }

  // per-memory spatial max of ptm (one wave handles memories wave, wave+4, ...)
  for (int m = wave; m < NMEM; m += 4) {
    const float* p = ptm + ((size_t)b * NMEM + m) * PIX;
    float mx = -INFINITY;
    for (int i = lane * 4; i < PIX; i += 256) {
      float4 v = *(const float4*)(p + i);
      mx = fmaxf(mx, fmaxf(fmaxf(v.x, v.y), fmaxf(v.z, v.w)));
    }
    #pragma unroll
    for (int off = 32; off > 0; off >>= 1)
      mx = fmaxf(mx, __shfl_down(mx, off, 64));
    if (lane == 0) s_pmax[m] = mx;
  }
  // max over target_scores
  {
    const float* p = ts + (size_t)b * PIX;
    float4 v = *(const float4*)(p + t * 4);
    float mx = fmaxf(fmaxf(v.x, v.y), fmaxf(v.z, v.w));
    #pragma unroll
    for (int off = 32; off > 0; off >>= 1)
      mx = fmaxf(mx, __shfl_down(mx, off, 64));
    if (lane == 0) s_red[wave] = mx;
  }
  __syncthreads();
  if (t == 0) {
    s_scal[0] = fmaxf(fmaxf(s_red[0], s_red[1]), fmaxf(s_red[2], s_red[3]));
    float sm = 0, sm2 = 0, sg = 0, sg2 = 0, so = 0, so2 = 0;
    for (int m = 0; m < NMEM; ++m) {
      float x = s_pmax[m];
      sm += s_mf[m] * x;  sm2 += s_mf[m] * x * x;
      sg += s_gth[m] * x; sg2 += s_gth[m] * x * x;
      so += s_oth[m] * x; so2 += s_oth[m] * x * x;
    }
    float cm = s_cnt[0], cg = s_cnt[1], co = s_cnt[2];
    float a = sm / cm; s_scal[1] = a; s_scal[2] = sqrtf(fmaxf(sm2 / cm - a * a, 0.f));
    float g = sg / cg; s_scal[3] = g; s_scal[4] = sqrtf(fmaxf(sg2 / cg - g * g, 0.f));
    float o = so / co; s_scal[5] = o; s_scal[6] = sqrtf(fmaxf(so2 / co - o * o, 0.f));
  }
  __syncthreads();

  // per-pixel pmt stats: each thread owns 4 consecutive pixels
  const int p0 = t * 4;
  float sA[4] = {0,0,0,0}, qA[4] = {0,0,0,0};
  float sG[4] = {0,0,0,0}, qG[4] = {0,0,0,0};
  float sO[4] = {0,0,0,0}, qO[4] = {0,0,0,0};
  const float* pb = pmt + (size_t)b * NMEM * PIX + p0;
  for (int m = 0; m < NMEM; ++m) {
    float4 v4 = *(const float4*)(pb + (size_t)m * PIX);
    float wm = s_mf[m], wo = s_oth[m];
    float xv[4] = {v4.x, v4.y, v4.z, v4.w};
    #pragma unroll
    for (int j = 0; j < 4; ++j) {
      float x = xv[j];
      sA[j] = fmaf(wm, x, sA[j]); qA[j] = fmaf(wm * x, x, qA[j]);
      sO[j] = fmaf(wo, x, sO[j]); qO[j] = fmaf(wo * x, x, qO[j]);
      if (m < NGTHC) { sG[j] += x; qG[j] = fmaf(x, x, qG[j]); }
    }
  }
  float cm = s_cnt[0], co = s_cnt[2];
  float* outb = inp + (size_t)b * 14 * PIX;
  float4 c2, c3, c4, c5, c6, c7;
  {
    float m0[4], d0[4], m1[4], d1[4], m2[4], d2[4];
    #pragma unroll
    for (int j = 0; j < 4; ++j) {
      m0[j] = sA[j] / cm;            d0[j] = sqrtf(fmaxf(qA[j] / cm - m0[j] * m0[j], 0.f));
      m1[j] = sG[j] / 15.f;          d1[j] = sqrtf(fmaxf(qG[j] / 15.f - m1[j] * m1[j], 0.f));
      m2[j] = sO[j] / co;            d2[j] = sqrtf(fmaxf(qO[j] / co - m2[j] * m2[j], 0.f));
    }
    c2 = make_float4(m0[0], m0[1], m0[2], m0[3]);
    c3 = make_float4(d0[0], d0[1], d0[2], d0[3]);
    c4 = make_float4(m1[0], m1[1], m1[2], m1[3]);
    c5 = make_float4(d1[0], d1[1], d1[2], d1[3]);
    c6 = make_float4(m2[0], m2[1], m2[2], m2[3]);
    c7 = make_float4(d2[0], d2[1], d2[2], d2[3]);
  }
  float pio = piou[b];
  float4 f;
  f = make_float4(s_scal[0], s_scal[0], s_scal[0], s_scal[0]); *(float4*)(outb + 0 * PIX + p0) = f;
  f = make_float4(pio, pio, pio, pio);                         *(float4*)(outb + 1 * PIX + p0) = f;
  *(float4*)(outb + 2 * PIX + p0) = c2;
  *(float4*)(outb + 3 * PIX + p0) = c3;
  *(float4*)(outb + 4 * PIX + p0) = c4;
  *(float4*)(outb + 5 * PIX + p0) = c5;
  *(float4*)(outb + 6 * PIX + p0) = c6;
  *(float4*)(outb + 7 * PIX + p0) = c7;
  #pragma unroll
  for (int c = 0; c < 6; ++c) {
    float s = s_scal[1 + c];
    f = make_float4(s, s, s, s);
    *(float4*)(outb + (8 + c) * PIX + p0) = f;
  }
}

// ---------------------------------------------------------------------------
// K1: conv1 (14->64, 3x3 VALID on 32x32 -> 30x30) + bias+BN+ReLU + 2x2 maxpool
// -> x1 (B,64,15,15). One block per b. Input in LDS (stride-33 rows),
// weights via wave-uniform scalar loads from global.
// pool(relu(bn(x))) == relu(bn(pool(x))) since bn scale > 0.
// ---------------------------------------------------------------------------
__global__ __launch_bounds__(256) void k1_conv1(
    const float* __restrict__ inp, const float* __restrict__ wgt,
    const float* __restrict__ bias, const float* __restrict__ gam,
    const float* __restrict__ bet, const float* __restrict__ mu,
    const float* __restrict__ var, float* __restrict__ x1)
{
  __shared__ float s_in[14 * 32 * 33];  // 59,136 B
  const int b = blockIdx.x, t = threadIdx.x;
  // stage input (14*1024 floats) with row stride 33
  for (int i = t; i < 14 * 1024 / 4; i += 256) {
    float4 v = *(const float4*)(inp + (size_t)b * 14 * 1024 + i * 4);
    int idx = i * 4;
    int c = idx >> 10, r = (idx >> 5) & 31, col = idx & 31;
    float* d = s_in + (c * 32 + r) * 33 + col;
    d[0] = v.x; d[1] = v.y; d[2] = v.z; d[3] = v.w;
  }
  __syncthreads();
  if (t >= 225) return;
  const int pr = t / 15, pc = t % 15;
  const int r0 = pr * 2, c0 = pc * 2;
  for (int cgi = 0; cgi < 4; ++cgi) {       // 4 chunks of 16 out-channels
    float acc[16][4];
    #pragma unroll
    for (int c = 0; c < 16; ++c) { acc[c][0]=0.f; acc[c][1]=0.f; acc[c][2]=0.f; acc[c][3]=0.f; }
    for (int ci = 0; ci < 14; ++ci) {
      float win[4][4];
      const float* src = s_in + (ci * 32 + r0) * 33 + c0;
      #pragma unroll
      for (int i = 0; i < 4; ++i)
        #pragma unroll
        for (int j = 0; j < 4; ++j) win[i][j] = src[i * 33 + j];
      #pragma unroll
      for (int c = 0; c < 16; ++c) {
        const int ch = cgi * 16 + c;
        const float* wp = wgt + ch * 126 + ci * 9;  // uniform -> s_load
        #pragma unroll
        for (int k = 0; k < 9; ++k) {
          const int kr = k / 3, kc = k % 3;
          float wv = wp[k];
          acc[c][0] = fmaf(wv, win[kr][kc],       acc[c][0]);
          acc[c][1] = fmaf(wv, win[kr][kc + 1],   acc[c][1]);
          acc[c][2] = fmaf(wv, win[kr + 1][kc],   acc[c][2]);
          acc[c][3] = fmaf(wv, win[kr + 1][kc + 1], acc[c][3]);
        }
      }
    }
    #pragma unroll
    for (int c = 0; c < 16; ++c) {
      const int ch = cgi * 16 + c;
      float sc = gam[ch] * rsqrtf(var[ch] + EPSF);
      float sh = (bias[ch] - mu[ch]) * sc + bet[ch];
      float mx = fmaxf(fmaxf(acc[c][0], acc[c][1]), fmaxf(acc[c][2], acc[c][3]));
      x1[((size_t)b * 64 + ch) * 225 + t] = fmaxf(mx * sc + sh, 0.f);
    }
  }
}

// ---------------------------------------------------------------------------
// K2/K3: 64->64 3x3 VALID conv + BN + ReLU. Two blocks per b, each does 32
// out-channels. Input tile in LDS (odd natural row stride -> conflict-free),
// weights via wave-uniform scalar loads.
// ---------------------------------------------------------------------------
template<int IH, int OH>
__global__ __launch_bounds__(256) void k_conv3x3(
    const float* __restrict__ xin, const float* __restrict__ wgt,
    const float* __restrict__ bias, const float* __restrict__ gam,
    const float* __restrict__ bet, const float* __restrict__ mu,
    const float* __restrict__ var, float* __restrict__ xout)
{
  constexpr int IP = IH * IH;
  constexpr int OP = OH * OH;
  __shared__ float s_in[64 * IP];   // IH odd -> natural stride is bank-friendly
  const int b = blockIdx.x >> 1, half = blockIdx.x & 1;
  const int t = threadIdx.x;
  const float* src = xin + (size_t)b * 64 * IP;
  for (int i = t; i < 64 * IP / 4; i += 256) {
    *(float4*)(s_in + i * 4) = *(const float4*)(src + i * 4);
  }
  __syncthreads();
  if (t >= OP) return;
  const int pr = t / OH, pc = t % OH;
  float acc[32];
  #pragma unroll
  for (int o = 0; o < 32; ++o) acc[o] = 0.f;
  for (int ci = 0; ci < 64; ++ci) {
    float win[9];
    const float* ip = s_in + (ci * IH + pr) * IH + pc;
    #pragma unroll
    for (int i = 0; i < 3; ++i)
      #pragma unroll
      for (int j = 0; j < 3; ++j) win[i * 3 + j] = ip[i * IH + j];
    #pragma unroll
    for (int o = 0; o < 32; ++o) {
      const float* wp = wgt + (half * 32 + o) * 576 + ci * 9;  // uniform -> s_load
      #pragma unroll
      for (int k = 0; k < 9; ++k) acc[o] = fmaf(wp[k], win[k], acc[o]);
    }
  }
  #pragma unroll
  for (int o = 0; o < 32; ++o) {
    const int ch = half * 32 + o;
    float sc = gam[ch] * rsqrtf(var[ch] + EPSF);
    float sh = (bias[ch] - mu[ch]) * sc + bet[ch];
    xout[((size_t)b * 64 + ch) * OP + t] = fmaxf(acc[o] * sc + sh, 0.f);
  }
}

// ---------------------------------------------------------------------------
// K4: conv4 (64->1, 3x3 on 11x11 -> 9x9) + bias + global max -> out (B,)
// ---------------------------------------------------------------------------
__global__ __launch_bounds__(128) void k4_conv4max(
    const float* __restrict__ x3, const float* __restrict__ w4,
    const float* __restrict__ b4, float* __restrict__ out)
{
  __shared__ float s_in[64 * 121];
  __shared__ float s_w[576];
  __shared__ float s_red[2];
  const int b = blockIdx.x, t = threadIdx.x;
  const float* src = x3 + (size_t)b * 64 * 121;
  for (int i = t; i < 64 * 121 / 4; i += 128)
    *(float4*)(s_in + i * 4) = *(const float4*)(src + i * 4);
  for (int i = t; i < 576; i += 128) s_w[i] = w4[i];
  __syncthreads();
  float val = -INFINITY;
  if (t < 81) {
    const int pr = t / 9, pc = t % 9;
    float acc = 0.f;
    for (int ci = 0; ci < 64; ++ci) {
      const float* ip = s_in + ci * 121 + pr * 11 + pc;
      const float* wp = s_w + ci * 9;
      #pragma unroll
      for (int i = 0; i < 3; ++i)
        #pragma unroll
        for (int j = 0; j < 3; ++j) acc = fmaf(ip[i * 11 + j], wp[i * 3 + j], acc);
    }
    val = acc;
  }
  #pragma unroll
  for (int off = 32; off > 0; off >>= 1)
    val = fmaxf(val, __shfl_down(val, off, 64));
  if ((t & 63) == 0) s_red[t >> 6] = val;
  __syncthreads();
  if (t == 0) out[b] = fmaxf(s_red[0], s_red[1]) + b4[0];
}

// ---------------------------------------------------------------------------
extern "C" void kernel_launch(void* const* d_in, const int* in_sizes, int n_in,
                              void* d_out, int out_size, void* d_ws, size_t ws_size,
                              hipStream_t stream) {
  const float* ts   = (const float*)d_in[0];
  const float* ptm  = (const float*)d_in[1];
  const float* pmt  = (const float*)d_in[2];
  const float* piou = (const float*)d_in[3];
  const int*   mask = (const int*)d_in[4];
  const float* c1w = (const float*)d_in[5];
  const float* c1b = (const float*)d_in[6];
  const float* g1  = (const float*)d_in[7];
  const float* b1  = (const float*)d_in[8];
  const float* m1  = (const float*)d_in[9];
  const float* v1  = (const float*)d_in[10];
  const float* c2w = (const float*)d_in[11];
  const float* c2b = (const float*)d_in[12];
  const float* g2  = (const float*)d_in[13];
  const float* b2  = (const float*)d_in[14];
  const float* m2  = (const float*)d_in[15];
  const float* v2  = (const float*)d_in[16];
  const float* c3w = (const float*)d_in[17];
  const float* c3b = (const float*)d_in[18];
  const float* g3  = (const float*)d_in[19];
  const float* b3  = (const float*)d_in[20];
  const float* m3  = (const float*)d_in[21];
  const float* v3  = (const float*)d_in[22];
  const float* c4w = (const float*)d_in[23];
  const float* c4b = (const float*)d_in[24];

  float* ws  = (float*)d_ws;
  float* inp = ws;                       // 512*14*1024 = 7,340,032 floats
  float* x1  = ws + 7340032;             // 512*64*225  = 7,372,800 floats
  float* x2  = ws;                       // reuse inp region (512*64*169)
  float* x3  = ws + 7340032;             // reuse x1 region (512*64*121)

  k0_stats<<<NFB, 256, 0, stream>>>(ts, ptm, pmt, piou, mask, inp);
  k1_conv1<<<NFB, 256, 0, stream>>>(inp, c1w, c1b, g1, b1, m1, v1, x1);
  k_conv3x3<15, 13><<<NFB * 2, 256, 0, stream>>>(x1, c2w, c2b, g2, b2, m2, v2, x2);
  k_conv3x3<13, 11><<<NFB * 2, 256, 0, stream>>>(x2, c3w, c3b, g3, b3, m3, v3, x3);
  k4_conv4max<<<NFB, 128, 0, stream>>>(x3, c4w, c4b, (float*)d_out);
}

// Round 2
// 1102.357 us; speedup vs baseline: 1.1564x; 1.1564x over previous
//
#include <hip/hip_runtime.h>
#include <math.h>

#define NFB  512     // B = nf*ns
#define NMEM 30
#define PIX  1024    // 32*32
#define EPSF 1e-5f

// workspace layout (float offsets). ws_size >= 58,851,328 B (round-1 usage).
// A: [0, 7864320)            x1 (512*64*15*16), later x3 (512*64*11*16)
// B: [7864320, ...)          img6 (512*6*1024) then x2 (512*64*13*16)
// scal at B + 6815744        (512*8)
#define OFF_B   7864320
#define OFF_SCAL (OFF_B + 6815744)

// ---------------------------------------------------------------------------
// K0: stats. Writes img6 (B,6,32,32) = the 6 non-uniform conv-input channels
// (pmt_mean, pmt_std, gth_mean, gth_std, oth_mean, oth_std) and scal (B,8) =
// {max_ts, piou, m_mm, s_mm, m_gm, s_gm, m_om, s_om} (the 8 uniform channels).
// ---------------------------------------------------------------------------
__global__ __launch_bounds__(256) void k0_stats(
    const float* __restrict__ ts, const float* __restrict__ ptm,
    const float* __restrict__ pmt, const float* __restrict__ piou,
    const int* __restrict__ mask, float* __restrict__ img6,
    float* __restrict__ scal)
{
  const int b = blockIdx.x;
  const int t = threadIdx.x;
  const int wave = t >> 6, lane = t & 63;
  __shared__ float s_mf[NMEM], s_gth[NMEM], s_oth[NMEM];
  __shared__ float s_pmax[NMEM];
  __shared__ float s_red[4];
  __shared__ float s_cnt[3];   // cnt_m, cnt_g, cnt_o

  if (t == 0) {
    float cum = 0.f, cm = 0.f, cg = 0.f, co = 0.f;
    for (int m = 0; m < NMEM; ++m) {
      float f  = (mask[b * NMEM + m] != 0) ? 1.f : 0.f;
      float gg = (cum < 15.f) ? f : 0.f;
      float oo = f - gg;
      cum += f;
      s_mf[m] = f; s_gth[m] = gg; s_oth[m] = oo;
      cm += f; cg += gg; co += oo;
    }
    s_cnt[0] = cm; s_cnt[1] = cg; s_cnt[2] = co;
  }

  // per-memory spatial max of ptm
  for (int m = wave; m < NMEM; m += 4) {
    const float* p = ptm + ((size_t)b * NMEM + m) * PIX;
    float mx = -INFINITY;
    for (int i = lane * 4; i < PIX; i += 256) {
      float4 v = *(const float4*)(p + i);
      mx = fmaxf(mx, fmaxf(fmaxf(v.x, v.y), fmaxf(v.z, v.w)));
    }
    #pragma unroll
    for (int off = 32; off > 0; off >>= 1)
      mx = fmaxf(mx, __shfl_down(mx, off, 64));
    if (lane == 0) s_pmax[m] = mx;
  }
  // max over target_scores
  {
    const float* p = ts + (size_t)b * PIX;
    float4 v = *(const float4*)(p + t * 4);
    float mx = fmaxf(fmaxf(v.x, v.y), fmaxf(v.z, v.w));
    #pragma unroll
    for (int off = 32; off > 0; off >>= 1)
      mx = fmaxf(mx, __shfl_down(mx, off, 64));
    if (lane == 0) s_red[wave] = mx;
  }
  __syncthreads();
  if (t == 0) {
    float maxts = fmaxf(fmaxf(s_red[0], s_red[1]), fmaxf(s_red[2], s_red[3]));
    float sm = 0, sm2 = 0, sg = 0, sg2 = 0, so = 0, so2 = 0;
    for (int m = 0; m < NMEM; ++m) {
      float x = s_pmax[m];
      sm += s_mf[m] * x;  sm2 += s_mf[m] * x * x;
      sg += s_gth[m] * x; sg2 += s_gth[m] * x * x;
      so += s_oth[m] * x; so2 += s_oth[m] * x * x;
    }
    float cm = s_cnt[0], cg = s_cnt[1], co = s_cnt[2];
    float a = sm / cm, g = sg / cg, o = so / co;
    float* sp = scal + b * 8;
    sp[0] = maxts; sp[1] = piou[b];
    sp[2] = a; sp[3] = sqrtf(fmaxf(sm2 / cm - a * a, 0.f));
    sp[4] = g; sp[5] = sqrtf(fmaxf(sg2 / cg - g * g, 0.f));
    sp[6] = o; sp[7] = sqrtf(fmaxf(so2 / co - o * o, 0.f));
  }

  // per-pixel pmt stats: each thread owns 4 consecutive pixels
  const int p0 = t * 4;
  float sA[4] = {0,0,0,0}, qA[4] = {0,0,0,0};
  float sG[4] = {0,0,0,0}, qG[4] = {0,0,0,0};
  float sO[4] = {0,0,0,0}, qO[4] = {0,0,0,0};
  const float* pb = pmt + (size_t)b * NMEM * PIX + p0;
  for (int m = 0; m < NMEM; ++m) {
    float4 v4 = *(const float4*)(pb + (size_t)m * PIX);
    float wm = s_mf[m], wo = s_oth[m];
    float xv[4] = {v4.x, v4.y, v4.z, v4.w};
    #pragma unroll
    for (int j = 0; j < 4; ++j) {
      float x = xv[j];
      sA[j] = fmaf(wm, x, sA[j]); qA[j] = fmaf(wm * x, x, qA[j]);
      sO[j] = fmaf(wo, x, sO[j]); qO[j] = fmaf(wo * x, x, qO[j]);
      if (m < 15) { sG[j] += x; qG[j] = fmaf(x, x, qG[j]); }
    }
  }
  float cm = s_cnt[0], co = s_cnt[2];
  float* ob = img6 + (size_t)b * 6144 + p0;
  float m0[4], d0[4], m1[4], d1[4], m2[4], d2[4];
  #pragma unroll
  for (int j = 0; j < 4; ++j) {
    m0[j] = sA[j] / cm;   d0[j] = sqrtf(fmaxf(qA[j] / cm - m0[j] * m0[j], 0.f));
    m1[j] = sG[j] / 15.f; d1[j] = sqrtf(fmaxf(qG[j] / 15.f - m1[j] * m1[j], 0.f));
    m2[j] = sO[j] / co;   d2[j] = sqrtf(fmaxf(qO[j] / co - m2[j] * m2[j], 0.f));
  }
  *(float4*)(ob + 0 * PIX) = make_float4(m0[0], m0[1], m0[2], m0[3]);
  *(float4*)(ob + 1 * PIX) = make_float4(d0[0], d0[1], d0[2], d0[3]);
  *(float4*)(ob + 2 * PIX) = make_float4(m1[0], m1[1], m1[2], m1[3]);
  *(float4*)(ob + 3 * PIX) = make_float4(d1[0], d1[1], d1[2], d1[3]);
  *(float4*)(ob + 4 * PIX) = make_float4(m2[0], m2[1], m2[2], m2[3]);
  *(float4*)(ob + 5 * PIX) = make_float4(d2[0], d2[1], d2[2], d2[3]);
}

// ---------------------------------------------------------------------------
// K1: conv1 on the 6 image channels + per-oc constant for the 8 uniform
// channels, + bias+BN+ReLU + 2x2 maxpool -> x1 (B,64,15,16) padded.
// lane = oc (weights in VGPRs); wave handles 4 pool rows (wave3: 3).
// ---------------------------------------------------------------------------
__global__ __launch_bounds__(256) void k1_conv1(
    const float* __restrict__ img6, const float* __restrict__ scal,
    const float* __restrict__ wgt, const float* __restrict__ bias,
    const float* __restrict__ gam, const float* __restrict__ bet,
    const float* __restrict__ mu, const float* __restrict__ var,
    float* __restrict__ x1)
{
  __shared__ float s_img[6 * 1024];   // [c][32][32], rows 128B-aligned
  const int b = blockIdx.x, t = threadIdx.x, lane = t & 63, wave = t >> 6;
  const float* src = img6 + (size_t)b * 6144;
  for (int i = t; i < 1536; i += 256)
    ((float4*)s_img)[i] = ((const float4*)src)[i];

  const int oc = lane;
  const float* wp = wgt + oc * 126;  // [oc][14][9]
  float cw[54];
  #pragma unroll
  for (int j = 0; j < 54; ++j) cw[j] = wp[18 + j];   // channels 2..7
  float cst = 0.f;
  {
    const int uch[8] = {0, 1, 8, 9, 10, 11, 12, 13};
    const float* sp = scal + b * 8;
    #pragma unroll
    for (int u = 0; u < 8; ++u) {
      float s = 0.f;
      #pragma unroll
      for (int k = 0; k < 9; ++k) s += wp[uch[u] * 9 + k];
      cst += s * sp[u];
    }
  }
  float scv = gam[oc] * rsqrtf(var[oc] + EPSF);
  float shv = (bias[oc] - mu[oc]) * scv + bet[oc];
  __syncthreads();

  const int npr = (wave == 3) ? 3 : 4;
  for (int q = 0; q < 4; ++q) {
    if (q < npr) {
      const int pr = wave * 4 + q;
      const int r0 = pr * 2;
      float a0[30], a1[30];
      #pragma unroll
      for (int c = 0; c < 30; ++c) { a0[c] = 0.f; a1[c] = 0.f; }
      #pragma unroll
      for (int ci = 0; ci < 6; ++ci) {
        #pragma unroll
        for (int wr = 0; wr < 4; ++wr) {
          float rr[32];
          const float4* rp = (const float4*)(s_img + ci * 1024 + (r0 + wr) * 32);
          #pragma unroll
          for (int j = 0; j < 8; ++j) {
            float4 v = rp[j];
            rr[4*j] = v.x; rr[4*j+1] = v.y; rr[4*j+2] = v.z; rr[4*j+3] = v.w;
          }
          if (wr < 3) {
            #pragma unroll
            for (int col = 0; col < 30; ++col)
              #pragma unroll
              for (int kc = 0; kc < 3; ++kc)
                a0[col] = fmaf(cw[ci * 9 + wr * 3 + kc], rr[col + kc], a0[col]);
          }
          if (wr >= 1) {
            #pragma unroll
            for (int col = 0; col < 30; ++col)
              #pragma unroll
              for (int kc = 0; kc < 3; ++kc)
                a1[col] = fmaf(cw[ci * 9 + (wr - 1) * 3 + kc], rr[col + kc], a1[col]);
          }
        }
      }
      #pragma unroll
      for (int pc = 0; pc < 15; ++pc) {
        float m = fmaxf(fmaxf(a0[2*pc], a0[2*pc+1]), fmaxf(a1[2*pc], a1[2*pc+1]));
        x1[(((size_t)b * 64 + oc) * 15 + pr) * 16 + pc] =
            fmaxf(scv * (m + cst) + shv, 0.f);
      }
    }
  }
}

// ---------------------------------------------------------------------------
// K2/K3: 64->64 3x3 VALID conv + BN + ReLU, weight-stationary.
// xin: [b][64][IH][16] padded; xout: [b][64][OH][16] padded.
// lane = oc; wave handles a contiguous band of output rows.
// Input windows: wave-uniform ds_read_b128 broadcasts (conflict-free).
// ---------------------------------------------------------------------------
template<int IH, int OH>
__global__ __launch_bounds__(256) void k_conv3x3(
    const float* __restrict__ xin, const float* __restrict__ wgt,
    const float* __restrict__ bias, const float* __restrict__ gam,
    const float* __restrict__ bet, const float* __restrict__ mu,
    const float* __restrict__ var, float* __restrict__ xout)
{
  constexpr int NRMAX = (OH + 3) / 4;
  constexpr int BASE = OH / 4, REM = OH % 4;
  __shared__ float s_in[64 * IH * 16];
  const int b = blockIdx.x, t = threadIdx.x, lane = t & 63, wave = t >> 6;
  const float* src = xin + (size_t)b * 64 * IH * 16;
  for (int i = t; i < 64 * IH * 4; i += 256)
    ((float4*)s_in)[i] = ((const float4*)src)[i];

  const int oc = lane;
  const int r0 = wave * BASE + (wave < REM ? wave : REM);
  const int nr = BASE + (wave < REM ? 1 : 0);
  float scv = gam[oc] * rsqrtf(var[oc] + EPSF);
  float shv = (bias[oc] - mu[oc]) * scv + bet[oc];
  float acc[NRMAX][OH];
  #pragma unroll
  for (int r = 0; r < NRMAX; ++r)
    #pragma unroll
    for (int c = 0; c < OH; ++c) acc[r][c] = 0.f;
  __syncthreads();

  #pragma unroll 1
  for (int chunk = 0; chunk < 8; ++chunk) {
    float ww[72];
    const float4* wp = (const float4*)(wgt + ((size_t)oc * 64 + chunk * 8) * 9);
    #pragma unroll
    for (int j = 0; j < 18; ++j) {
      float4 v = wp[j];
      ww[4*j] = v.x; ww[4*j+1] = v.y; ww[4*j+2] = v.z; ww[4*j+3] = v.w;
    }
    #pragma unroll
    for (int cil = 0; cil < 8; ++cil) {
      const int ci = chunk * 8 + cil;
      #pragma unroll
      for (int wr = 0; wr < NRMAX + 2; ++wr) {
        if (wr < nr + 2) {   // wave-uniform guard
          float rr[16];
          const float4* rp = (const float4*)(s_in + (ci * IH + r0 + wr) * 16);
          #pragma unroll
          for (int j = 0; j < 4; ++j) {
            float4 v = rp[j];
            rr[4*j] = v.x; rr[4*j+1] = v.y; rr[4*j+2] = v.z; rr[4*j+3] = v.w;
          }
          #pragma unroll
          for (int rl = 0; rl < NRMAX; ++rl) {
            const int kr = wr - rl;
            if (kr >= 0 && kr <= 2) {       // compile-time prune
              if (rl < nr) {                // wave-uniform guard
                #pragma unroll
                for (int c = 0; c < OH; ++c)
                  #pragma unroll
                  for (int kc = 0; kc < 3; ++kc)
                    acc[rl][c] = fmaf(ww[cil * 9 + kr * 3 + kc], rr[c + kc], acc[rl][c]);
              }
            }
          }
        }
      }
    }
  }
  #pragma unroll
  for (int rl = 0; rl < NRMAX; ++rl) {
    if (rl < nr) {
      #pragma unroll
      for (int c = 0; c < OH; ++c) {
        float y = fmaxf(acc[rl][c] * scv + shv, 0.f);
        xout[(((size_t)b * 64 + oc) * OH + (r0 + rl)) * 16 + c] = y;
      }
    }
  }
}

// ---------------------------------------------------------------------------
// K4: conv4 (64->1, 3x3 on 11x11 -> 9x9) + bias + global max -> out (B,)
// x3 padded [b][64][11][16].
// ---------------------------------------------------------------------------
__global__ __launch_bounds__(128) void k4_conv4max(
    const float* __restrict__ x3, const float* __restrict__ w4,
    const float* __restrict__ b4, float* __restrict__ out)
{
  __shared__ float s_in[64 * 11 * 16];   // 45,056 B
  __shared__ float s_w[576];
  __shared__ float s_red[2];
  const int b = blockIdx.x, t = threadIdx.x;
  const float* src = x3 + (size_t)b * 64 * 176;
  for (int i = t; i < 2816; i += 128)
    ((float4*)s_in)[i] = ((const float4*)src)[i];
  for (int i = t; i < 576; i += 128) s_w[i] = w4[i];
  __syncthreads();
  float val = -INFINITY;
  if (t < 81) {
    const int pr = t / 9, pc = t % 9;
    float acc = 0.f;
    for (int ci = 0; ci < 64; ++ci) {
      const float* ip = s_in + ci * 176 + pr * 16 + pc;
      const float* wp = s_w + ci * 9;
      #pragma unroll
      for (int i = 0; i < 3; ++i)
        #pragma unroll
        for (int j = 0; j < 3; ++j) acc = fmaf(ip[i * 16 + j], wp[i * 3 + j], acc);
    }
    val = acc;
  }
  #pragma unroll
  for (int off = 32; off > 0; off >>= 1)
    val = fmaxf(val, __shfl_down(val, off, 64));
  if ((t & 63) == 0) s_red[t >> 6] = val;
  __syncthreads();
  if (t == 0) out[b] = fmaxf(s_red[0], s_red[1]) + b4[0];
}

// ---------------------------------------------------------------------------
extern "C" void kernel_launch(void* const* d_in, const int* in_sizes, int n_in,
                              void* d_out, int out_size, void* d_ws, size_t ws_size,
                              hipStream_t stream) {
  const float* ts   = (const float*)d_in[0];
  const float* ptm  = (const float*)d_in[1];
  const float* pmt  = (const float*)d_in[2];
  const float* piou = (const float*)d_in[3];
  const int*   mask = (const int*)d_in[4];
  const float* c1w = (const float*)d_in[5];
  const float* c1b = (const float*)d_in[6];
  const float* g1  = (const float*)d_in[7];
  const float* b1  = (const float*)d_in[8];
  const float* m1  = (const float*)d_in[9];
  const float* v1  = (const float*)d_in[10];
  const float* c2w = (const float*)d_in[11];
  const float* c2b = (const float*)d_in[12];
  const float* g2  = (const float*)d_in[13];
  const float* b2  = (const float*)d_in[14];
  const float* m2  = (const float*)d_in[15];
  const float* v2  = (const float*)d_in[16];
  const float* c3w = (const float*)d_in[17];
  const float* c3b = (const float*)d_in[18];
  const float* g3  = (const float*)d_in[19];
  const float* b3  = (const float*)d_in[20];
  const float* m3  = (const float*)d_in[21];
  const float* v3  = (const float*)d_in[22];
  const float* c4w = (const float*)d_in[23];
  const float* c4b = (const float*)d_in[24];

  float* ws   = (float*)d_ws;
  float* x1   = ws;                  // A
  float* img6 = ws + OFF_B;          // B (dead after k1)
  float* x2   = ws + OFF_B;          // B (overwrites img6)
  float* scal = ws + OFF_SCAL;
  float* x3   = ws;                  // A (overwrites dead x1)

  k0_stats<<<NFB, 256, 0, stream>>>(ts, ptm, pmt, piou, mask, img6, scal);
  k1_conv1<<<NFB, 256, 0, stream>>>(img6, scal, c1w, c1b, g1, b1, m1, v1, x1);
  k_conv3x3<15, 13><<<NFB, 256, 0, stream>>>(x1, c2w, c2b, g2, b2, m2, v2, x2);
  k_conv3x3<13, 11><<<NFB, 256, 0, stream>>>(x2, c3w, c3b, g3, b3, m3, v3, x3);
  k4_conv4max<<<NFB, 128, 0, stream>>>(x3, c4w, c4b, (float*)d_out);
}

// Round 3
// 593.801 us; speedup vs baseline: 2.1468x; 1.8564x over previous
//
#include <hip/hip_runtime.h>
#include <math.h>

#define NFB  512     // B = nf*ns
#define NMEM 30
#define PIX  1024    // 32*32
#define EPSF 1e-5f

// workspace layout (float offsets), peak usage identical to round 1/2.
// A: [0, 7864320)            x1 (512*64*15*16), later x3 (512*64*11*16)
// B: [7864320, ...)          img6 (512*6*1024) then x2 (512*64*13*16)
// scal at B + 6815744        (512*8)
#define OFF_B   7864320
#define OFF_SCAL (OFF_B + 6815744)

// ---------------------------------------------------------------------------
// K0: stats. Writes img6 (B,6,32,32) = the 6 non-uniform conv-input channels
// (pmt_mean, pmt_std, gth_mean, gth_std, oth_mean, oth_std) and scal (B,8) =
// {max_ts, piou, m_mm, s_mm, m_gm, s_gm, m_om, s_om} (the 8 uniform channels).
// ---------------------------------------------------------------------------
__global__ __launch_bounds__(256) void k0_stats(
    const float* __restrict__ ts, const float* __restrict__ ptm,
    const float* __restrict__ pmt, const float* __restrict__ piou,
    const int* __restrict__ mask, float* __restrict__ img6,
    float* __restrict__ scal)
{
  const int b = blockIdx.x;
  const int t = threadIdx.x;
  const int wave = t >> 6, lane = t & 63;
  __shared__ float s_mf[NMEM], s_gth[NMEM], s_oth[NMEM];
  __shared__ float s_pmax[NMEM];
  __shared__ float s_red[4];
  __shared__ float s_cnt[3];   // cnt_m, cnt_g, cnt_o

  if (t == 0) {
    float cum = 0.f, cm = 0.f, cg = 0.f, co = 0.f;
    for (int m = 0; m < NMEM; ++m) {
      float f  = (mask[b * NMEM + m] != 0) ? 1.f : 0.f;
      float gg = (cum < 15.f) ? f : 0.f;
      float oo = f - gg;
      cum += f;
      s_mf[m] = f; s_gth[m] = gg; s_oth[m] = oo;
      cm += f; cg += gg; co += oo;
    }
    s_cnt[0] = cm; s_cnt[1] = cg; s_cnt[2] = co;
  }

  // per-memory spatial max of ptm
  for (int m = wave; m < NMEM; m += 4) {
    const float* p = ptm + ((size_t)b * NMEM + m) * PIX;
    float mx = -INFINITY;
    for (int i = lane * 4; i < PIX; i += 256) {
      float4 v = *(const float4*)(p + i);
      mx = fmaxf(mx, fmaxf(fmaxf(v.x, v.y), fmaxf(v.z, v.w)));
    }
    #pragma unroll
    for (int off = 32; off > 0; off >>= 1)
      mx = fmaxf(mx, __shfl_down(mx, off, 64));
    if (lane == 0) s_pmax[m] = mx;
  }
  // max over target_scores
  {
    const float* p = ts + (size_t)b * PIX;
    float4 v = *(const float4*)(p + t * 4);
    float mx = fmaxf(fmaxf(v.x, v.y), fmaxf(v.z, v.w));
    #pragma unroll
    for (int off = 32; off > 0; off >>= 1)
      mx = fmaxf(mx, __shfl_down(mx, off, 64));
    if (lane == 0) s_red[wave] = mx;
  }
  __syncthreads();
  if (t == 0) {
    float maxts = fmaxf(fmaxf(s_red[0], s_red[1]), fmaxf(s_red[2], s_red[3]));
    float sm = 0, sm2 = 0, sg = 0, sg2 = 0, so = 0, so2 = 0;
    for (int m = 0; m < NMEM; ++m) {
      float x = s_pmax[m];
      sm += s_mf[m] * x;  sm2 += s_mf[m] * x * x;
      sg += s_gth[m] * x; sg2 += s_gth[m] * x * x;
      so += s_oth[m] * x; so2 += s_oth[m] * x * x;
    }
    float cm = s_cnt[0], cg = s_cnt[1], co = s_cnt[2];
    float a = sm / cm, g = sg / cg, o = so / co;
    float* sp = scal + b * 8;
    sp[0] = maxts; sp[1] = piou[b];
    sp[2] = a; sp[3] = sqrtf(fmaxf(sm2 / cm - a * a, 0.f));
    sp[4] = g; sp[5] = sqrtf(fmaxf(sg2 / cg - g * g, 0.f));
    sp[6] = o; sp[7] = sqrtf(fmaxf(so2 / co - o * o, 0.f));
  }

  // per-pixel pmt stats: each thread owns 4 consecutive pixels
  const int p0 = t * 4;
  float sA[4] = {0,0,0,0}, qA[4] = {0,0,0,0};
  float sG[4] = {0,0,0,0}, qG[4] = {0,0,0,0};
  float sO[4] = {0,0,0,0}, qO[4] = {0,0,0,0};
  const float* pb = pmt + (size_t)b * NMEM * PIX + p0;
  for (int m = 0; m < NMEM; ++m) {
    float4 v4 = *(const float4*)(pb + (size_t)m * PIX);
    float wm = s_mf[m], wo = s_oth[m];
    float xv[4] = {v4.x, v4.y, v4.z, v4.w};
    #pragma unroll
    for (int j = 0; j < 4; ++j) {
      float x = xv[j];
      sA[j] = fmaf(wm, x, sA[j]); qA[j] = fmaf(wm * x, x, qA[j]);
      sO[j] = fmaf(wo, x, sO[j]); qO[j] = fmaf(wo * x, x, qO[j]);
      if (m < 15) { sG[j] += x; qG[j] = fmaf(x, x, qG[j]); }
    }
  }
  float cm = s_cnt[0], co = s_cnt[2];
  float* ob = img6 + (size_t)b * 6144 + p0;
  float m0[4], d0[4], m1[4], d1[4], m2[4], d2[4];
  #pragma unroll
  for (int j = 0; j < 4; ++j) {
    m0[j] = sA[j] / cm;   d0[j] = sqrtf(fmaxf(qA[j] / cm - m0[j] * m0[j], 0.f));
    m1[j] = sG[j] / 15.f; d1[j] = sqrtf(fmaxf(qG[j] / 15.f - m1[j] * m1[j], 0.f));
    m2[j] = sO[j] / co;   d2[j] = sqrtf(fmaxf(qO[j] / co - m2[j] * m2[j], 0.f));
  }
  *(float4*)(ob + 0 * PIX) = make_float4(m0[0], m0[1], m0[2], m0[3]);
  *(float4*)(ob + 1 * PIX) = make_float4(d0[0], d0[1], d0[2], d0[3]);
  *(float4*)(ob + 2 * PIX) = make_float4(m1[0], m1[1], m1[2], m1[3]);
  *(float4*)(ob + 3 * PIX) = make_float4(d1[0], d1[1], d1[2], d1[3]);
  *(float4*)(ob + 4 * PIX) = make_float4(m2[0], m2[1], m2[2], m2[3]);
  *(float4*)(ob + 5 * PIX) = make_float4(d2[0], d2[1], d2[2], d2[3]);
}

// ---------------------------------------------------------------------------
// K1: conv1 on the 6 image channels + per-oc constant for the 8 uniform
// channels, + bias+BN+ReLU + 2x2 maxpool -> x1 (B,64,15,16) padded.
// lane = oc (weights in VGPRs); wave handles 4 pool rows (wave3: 3).
// ---------------------------------------------------------------------------
__global__ __launch_bounds__(256) void k1_conv1(
    const float* __restrict__ img6, const float* __restrict__ scal,
    const float* __restrict__ wgt, const float* __restrict__ bias,
    const float* __restrict__ gam, const float* __restrict__ bet,
    const float* __restrict__ mu, const float* __restrict__ var,
    float* __restrict__ x1)
{
  __shared__ float s_img[6 * 1024];   // [c][32][32], rows 128B-aligned
  const int b = blockIdx.x, t = threadIdx.x, lane = t & 63, wave = t >> 6;
  const float* src = img6 + (size_t)b * 6144;
  for (int i = t; i < 1536; i += 256)
    ((float4*)s_img)[i] = ((const float4*)src)[i];

  const int oc = lane;
  const float* wp = wgt + oc * 126;  // [oc][14][9]
  float cst = 0.f;
  {
    const int uch[8] = {0, 1, 8, 9, 10, 11, 12, 13};
    const float* sp = scal + b * 8;
    #pragma unroll
    for (int u = 0; u < 8; ++u) {
      float s = 0.f;
      #pragma unroll
      for (int k = 0; k < 9; ++k) s += wp[uch[u] * 9 + k];
      cst += s * sp[u];
    }
  }
  float scv = gam[oc] * rsqrtf(var[oc] + EPSF);
  float shv = (bias[oc] - mu[oc]) * scv + bet[oc];
  __syncthreads();

  const int npr = (wave == 3) ? 3 : 4;
  for (int q = 0; q < 4; ++q) {
    if (q < npr) {
      const int pr = wave * 4 + q;
      const int r0 = pr * 2;
      float a0[30], a1[30];
      #pragma unroll
      for (int c = 0; c < 30; ++c) { a0[c] = 0.f; a1[c] = 0.f; }
      #pragma unroll 1
      for (int ci = 0; ci < 6; ++ci) {
        // weights for this ci (channels 2..7 of the 14): 9 floats
        float cw[9];
        {
          const float4* wv = (const float4*)(wp + 18 + ci * 9);
          float4 w0 = wv[0], w1 = wv[1];
          cw[0]=w0.x; cw[1]=w0.y; cw[2]=w0.z; cw[3]=w0.w;
          cw[4]=w1.x; cw[5]=w1.y; cw[6]=w1.z; cw[7]=w1.w;
          cw[8]=wp[18 + ci * 9 + 8];
        }
        #pragma unroll
        for (int wr = 0; wr < 4; ++wr) {
          float rr[32];
          const float4* rp = (const float4*)(s_img + ci * 1024 + (r0 + wr) * 32);
          #pragma unroll
          for (int j = 0; j < 8; ++j) {
            float4 v = rp[j];
            rr[4*j] = v.x; rr[4*j+1] = v.y; rr[4*j+2] = v.z; rr[4*j+3] = v.w;
          }
          if (wr < 3) {
            #pragma unroll
            for (int col = 0; col < 30; ++col)
              #pragma unroll
              for (int kc = 0; kc < 3; ++kc)
                a0[col] = fmaf(cw[wr * 3 + kc], rr[col + kc], a0[col]);
          }
          if (wr >= 1) {
            #pragma unroll
            for (int col = 0; col < 30; ++col)
              #pragma unroll
              for (int kc = 0; kc < 3; ++kc)
                a1[col] = fmaf(cw[(wr - 1) * 3 + kc], rr[col + kc], a1[col]);
          }
        }
      }
      #pragma unroll
      for (int pc = 0; pc < 15; ++pc) {
        float m = fmaxf(fmaxf(a0[2*pc], a0[2*pc+1]), fmaxf(a1[2*pc], a1[2*pc+1]));
        x1[(((size_t)b * 64 + oc) * 15 + pr) * 16 + pc] =
            fmaxf(scv * (m + cst) + shv, 0.f);
      }
    }
  }
}

// ---------------------------------------------------------------------------
// K2/K3: 64->64 3x3 VALID conv + BN + ReLU, weight-stationary.
// xin: [b][64][IH][16] padded; xout: [b][64][OH][16] padded.
// lane = oc; wave handles a contiguous band of output rows.
// Input windows: wave-uniform ds_read_b128 broadcasts (conflict-free).
// Weight chunk = 4 input channels (36 VGPRs) to stay far below the
// 256-VGPR cap — round 2's 8-ci chunk spilled (2.26 GB scratch traffic).
// ---------------------------------------------------------------------------
template<int IH, int OH>
__global__ __launch_bounds__(256) void k_conv3x3(
    const float* __restrict__ xin, const float* __restrict__ wgt,
    const float* __restrict__ bias, const float* __restrict__ gam,
    const float* __restrict__ bet, const float* __restrict__ mu,
    const float* __restrict__ var, float* __restrict__ xout)
{
  constexpr int NRMAX = (OH + 3) / 4;
  constexpr int BASE = OH / 4, REM = OH % 4;
  __shared__ float s_in[64 * IH * 16];
  const int b = blockIdx.x, t = threadIdx.x, lane = t & 63, wave = t >> 6;
  const float* src = xin + (size_t)b * 64 * IH * 16;
  for (int i = t; i < 64 * IH * 4; i += 256)
    ((float4*)s_in)[i] = ((const float4*)src)[i];

  const int oc = lane;
  const int r0 = wave * BASE + (wave < REM ? wave : REM);
  const int nr = BASE + (wave < REM ? 1 : 0);
  float scv = gam[oc] * rsqrtf(var[oc] + EPSF);
  float shv = (bias[oc] - mu[oc]) * scv + bet[oc];
  float acc[NRMAX][OH];
  #pragma unroll
  for (int r = 0; r < NRMAX; ++r)
    #pragma unroll
    for (int c = 0; c < OH; ++c) acc[r][c] = 0.f;
  __syncthreads();

  #pragma unroll 1
  for (int chunk = 0; chunk < 16; ++chunk) {
    float ww[36];
    const float4* wp = (const float4*)(wgt + ((size_t)oc * 64 + chunk * 4) * 9);
    #pragma unroll
    for (int j = 0; j < 9; ++j) {
      float4 v = wp[j];
      ww[4*j] = v.x; ww[4*j+1] = v.y; ww[4*j+2] = v.z; ww[4*j+3] = v.w;
    }
    #pragma unroll
    for (int cil = 0; cil < 4; ++cil) {
      const int ci = chunk * 4 + cil;
      #pragma unroll
      for (int wr = 0; wr < NRMAX + 2; ++wr) {
        if (wr < nr + 2) {   // wave-uniform guard
          float rr[16];
          const float4* rp = (const float4*)(s_in + (ci * IH + r0 + wr) * 16);
          #pragma unroll
          for (int j = 0; j < 4; ++j) {
            float4 v = rp[j];
            rr[4*j] = v.x; rr[4*j+1] = v.y; rr[4*j+2] = v.z; rr[4*j+3] = v.w;
          }
          #pragma unroll
          for (int rl = 0; rl < NRMAX; ++rl) {
            const int kr = wr - rl;
            if (kr >= 0 && kr <= 2) {       // compile-time prune
              if (rl < nr) {                // wave-uniform guard
                #pragma unroll
                for (int c = 0; c < OH; ++c)
                  #pragma unroll
                  for (int kc = 0; kc < 3; ++kc)
                    acc[rl][c] = fmaf(ww[cil * 9 + kr * 3 + kc], rr[c + kc], acc[rl][c]);
              }
            }
          }
        }
      }
    }
  }
  #pragma unroll
  for (int rl = 0; rl < NRMAX; ++rl) {
    if (rl < nr) {
      #pragma unroll
      for (int c = 0; c < OH; ++c) {
        float y = fmaxf(acc[rl][c] * scv + shv, 0.f);
        xout[(((size_t)b * 64 + oc) * OH + (r0 + rl)) * 16 + c] = y;
      }
    }
  }
}

// ---------------------------------------------------------------------------
// K4: conv4 (64->1, 3x3 on 11x11 -> 9x9) + bias + global max -> out (B,)
// x3 padded [b][64][11][16].
// ---------------------------------------------------------------------------
__global__ __launch_bounds__(128) void k4_conv4max(
    const float* __restrict__ x3, const float* __restrict__ w4,
    const float* __restrict__ b4, float* __restrict__ out)
{
  __shared__ float s_in[64 * 11 * 16];   // 45,056 B
  __shared__ float s_w[576];
  __shared__ float s_red[2];
  const int b = blockIdx.x, t = threadIdx.x;
  const float* src = x3 + (size_t)b * 64 * 176;
  for (int i = t; i < 2816; i += 128)
    ((float4*)s_in)[i] = ((const float4*)src)[i];
  for (int i = t; i < 576; i += 128) s_w[i] = w4[i];
  __syncthreads();
  float val = -INFINITY;
  if (t < 81) {
    const int pr = t / 9, pc = t % 9;
    float acc = 0.f;
    for (int ci = 0; ci < 64; ++ci) {
      const float* ip = s_in + ci * 176 + pr * 16 + pc;
      const float* wp = s_w + ci * 9;
      #pragma unroll
      for (int i = 0; i < 3; ++i)
        #pragma unroll
        for (int j = 0; j < 3; ++j) acc = fmaf(ip[i * 16 + j], wp[i * 3 + j], acc);
    }
    val = acc;
  }
  #pragma unroll
  for (int off = 32; off > 0; off >>= 1)
    val = fmaxf(val, __shfl_down(val, off, 64));
  if ((t & 63) == 0) s_red[t >> 6] = val;
  __syncthreads();
  if (t == 0) out[b] = fmaxf(s_red[0], s_red[1]) + b4[0];
}

// ---------------------------------------------------------------------------
extern "C" void kernel_launch(void* const* d_in, const int* in_sizes, int n_in,
                              void* d_out, int out_size, void* d_ws, size_t ws_size,
                              hipStream_t stream) {
  const float* ts   = (const float*)d_in[0];
  const float* ptm  = (const float*)d_in[1];
  const float* pmt  = (const float*)d_in[2];
  const float* piou = (const float*)d_in[3];
  const int*   mask = (const int*)d_in[4];
  const float* c1w = (const float*)d_in[5];
  const float* c1b = (const float*)d_in[6];
  const float* g1  = (const float*)d_in[7];
  const float* b1  = (const float*)d_in[8];
  const float* m1  = (const float*)d_in[9];
  const float* v1  = (const float*)d_in[10];
  const float* c2w = (const float*)d_in[11];
  const float* c2b = (const float*)d_in[12];
  const float* g2  = (const float*)d_in[13];
  const float* b2  = (const float*)d_in[14];
  const float* m2  = (const float*)d_in[15];
  const float* v2  = (const float*)d_in[16];
  const float* c3w = (const float*)d_in[17];
  const float* c3b = (const float*)d_in[18];
  const float* g3  = (const float*)d_in[19];
  const float* b3  = (const float*)d_in[20];
  const float* m3  = (const float*)d_in[21];
  const float* v3  = (const float*)d_in[22];
  const float* c4w = (const float*)d_in[23];
  const float* c4b = (const float*)d_in[24];

  float* ws   = (float*)d_ws;
  float* x1   = ws;                  // A
  float* img6 = ws + OFF_B;          // B (dead after k1)
  float* x2   = ws + OFF_B;          // B (overwrites img6)
  float* scal = ws + OFF_SCAL;
  float* x3   = ws;                  // A (overwrites dead x1)

  k0_stats<<<NFB, 256, 0, stream>>>(ts, ptm, pmt, piou, mask, img6, scal);
  k1_conv1<<<NFB, 256, 0, stream>>>(img6, scal, c1w, c1b, g1, b1, m1, v1, x1);
  k_conv3x3<15, 13><<<NFB, 256, 0, stream>>>(x1, c2w, c2b, g2, b2, m2, v2, x2);
  k_conv3x3<13, 11><<<NFB, 256, 0, stream>>>(x2, c3w, c3b, g3, b3, m3, v3, x3);
  k4_conv4max<<<NFB, 128, 0, stream>>>(x3, c4w, c4b, (float*)d_out);
}

// Round 4
// 318.271 us; speedup vs baseline: 4.0053x; 1.8657x over previous
//
#include <hip/hip_runtime.h>
#include <math.h>

#define NFB  512     // B = nf*ns
#define NMEM 30
#define PIX  1024    // 32*32
#define EPSF 1e-5f

typedef _Float16 half8_t __attribute__((ext_vector_type(8)));
typedef _Float16 half4_t __attribute__((ext_vector_type(4)));
typedef float float4_t __attribute__((ext_vector_type(4)));

// workspace layout (byte offsets):
// img6  (fp32, 512*6*1024)            @ 0          size 12,582,912
// scal  (fp32, 512*8)                 @ 12,582,912 size 16,384
// x1h   (f16, 512*15*16*64)           @ 12,599,296 size 15,728,640
// x2h   (f16, 512*13*16*64)           @ 28,327,936 size 13,631,488
// x3h   (f16, 512*11*16*64)           @ 41,959,424 size 11,534,336
// w2rep (f16, 3*64*192)               @ 53,493,760 size 73,728
// w3rep (f16, 3*64*192)               @ 53,567,488 size 73,728   (end 53,641,216)
#define OFF_SCAL 12582912
#define OFF_X1H  12599296
#define OFF_X2H  28327936
#define OFF_X3H  41959424
#define OFF_W2R  53493760
#define OFF_W3R  53567488

// ---------------------------------------------------------------------------
// repack conv weights [oc][ci][3][3] fp32 -> [kr][oc][kc*64+ci] f16
// ---------------------------------------------------------------------------
__global__ __launch_bounds__(256) void k_repack(
    const float* __restrict__ w, _Float16* __restrict__ wr)
{
  int i = blockIdx.x * 256 + threadIdx.x;     // over 3*64*192 = 36864
  if (i < 36864) {
    int kr = i / 12288;
    int rem = i - kr * 12288;
    int oc = rem / 192;
    int k = rem - oc * 192;
    int kc = k >> 6, ci = k & 63;
    wr[i] = (_Float16)w[((oc * 64 + ci) * 3 + kr) * 3 + kc];
  }
}

// ---------------------------------------------------------------------------
// K0: stats -> img6 (B,6,32,32 fp32) + scal (B,8)
// ---------------------------------------------------------------------------
__global__ __launch_bounds__(256) void k0_stats(
    const float* __restrict__ ts, const float* __restrict__ ptm,
    const float* __restrict__ pmt, const float* __restrict__ piou,
    const int* __restrict__ mask, float* __restrict__ img6,
    float* __restrict__ scal)
{
  const int b = blockIdx.x;
  const int t = threadIdx.x;
  const int wave = t >> 6, lane = t & 63;
  __shared__ float s_mf[NMEM], s_gth[NMEM], s_oth[NMEM];
  __shared__ float s_pmax[NMEM];
  __shared__ float s_red[4];
  __shared__ float s_cnt[3];

  if (t == 0) {
    float cum = 0.f, cm = 0.f, cg = 0.f, co = 0.f;
    for (int m = 0; m < NMEM; ++m) {
      float f  = (mask[b * NMEM + m] != 0) ? 1.f : 0.f;
      float gg = (cum < 15.f) ? f : 0.f;
      float oo = f - gg;
      cum += f;
      s_mf[m] = f; s_gth[m] = gg; s_oth[m] = oo;
      cm += f; cg += gg; co += oo;
    }
    s_cnt[0] = cm; s_cnt[1] = cg; s_cnt[2] = co;
  }

  for (int m = wave; m < NMEM; m += 4) {
    const float* p = ptm + ((size_t)b * NMEM + m) * PIX;
    float mx = -INFINITY;
    for (int i = lane * 4; i < PIX; i += 256) {
      float4 v = *(const float4*)(p + i);
      mx = fmaxf(mx, fmaxf(fmaxf(v.x, v.y), fmaxf(v.z, v.w)));
    }
    #pragma unroll
    for (int off = 32; off > 0; off >>= 1)
      mx = fmaxf(mx, __shfl_down(mx, off, 64));
    if (lane == 0) s_pmax[m] = mx;
  }
  {
    const float* p = ts + (size_t)b * PIX;
    float4 v = *(const float4*)(p + t * 4);
    float mx = fmaxf(fmaxf(v.x, v.y), fmaxf(v.z, v.w));
    #pragma unroll
    for (int off = 32; off > 0; off >>= 1)
      mx = fmaxf(mx, __shfl_down(mx, off, 64));
    if (lane == 0) s_red[wave] = mx;
  }
  __syncthreads();
  if (t == 0) {
    float maxts = fmaxf(fmaxf(s_red[0], s_red[1]), fmaxf(s_red[2], s_red[3]));
    float sm = 0, sm2 = 0, sg = 0, sg2 = 0, so = 0, so2 = 0;
    for (int m = 0; m < NMEM; ++m) {
      float x = s_pmax[m];
      sm += s_mf[m] * x;  sm2 += s_mf[m] * x * x;
      sg += s_gth[m] * x; sg2 += s_gth[m] * x * x;
      so += s_oth[m] * x; so2 += s_oth[m] * x * x;
    }
    float cm = s_cnt[0], cg = s_cnt[1], co = s_cnt[2];
    float a = sm / cm, g = sg / cg, o = so / co;
    float* sp = scal + b * 8;
    sp[0] = maxts; sp[1] = piou[b];
    sp[2] = a; sp[3] = sqrtf(fmaxf(sm2 / cm - a * a, 0.f));
    sp[4] = g; sp[5] = sqrtf(fmaxf(sg2 / cg - g * g, 0.f));
    sp[6] = o; sp[7] = sqrtf(fmaxf(so2 / co - o * o, 0.f));
  }

  const int p0 = t * 4;
  float sA[4] = {0,0,0,0}, qA[4] = {0,0,0,0};
  float sG[4] = {0,0,0,0}, qG[4] = {0,0,0,0};
  float sO[4] = {0,0,0,0}, qO[4] = {0,0,0,0};
  const float* pb = pmt + (size_t)b * NMEM * PIX + p0;
  for (int m = 0; m < NMEM; ++m) {
    float4 v4 = *(const float4*)(pb + (size_t)m * PIX);
    float wm = s_mf[m], wo = s_oth[m];
    float xv[4] = {v4.x, v4.y, v4.z, v4.w};
    #pragma unroll
    for (int j = 0; j < 4; ++j) {
      float x = xv[j];
      sA[j] = fmaf(wm, x, sA[j]); qA[j] = fmaf(wm * x, x, qA[j]);
      sO[j] = fmaf(wo, x, sO[j]); qO[j] = fmaf(wo * x, x, qO[j]);
      if (m < 15) { sG[j] += x; qG[j] = fmaf(x, x, qG[j]); }
    }
  }
  float cm = s_cnt[0], co = s_cnt[2];
  float* ob = img6 + (size_t)b * 6144 + p0;
  float m0[4], d0[4], m1[4], d1[4], m2[4], d2[4];
  #pragma unroll
  for (int j = 0; j < 4; ++j) {
    m0[j] = sA[j] / cm;   d0[j] = sqrtf(fmaxf(qA[j] / cm - m0[j] * m0[j], 0.f));
    m1[j] = sG[j] / 15.f; d1[j] = sqrtf(fmaxf(qG[j] / 15.f - m1[j] * m1[j], 0.f));
    m2[j] = sO[j] / co;   d2[j] = sqrtf(fmaxf(qO[j] / co - m2[j] * m2[j], 0.f));
  }
  *(float4*)(ob + 0 * PIX) = make_float4(m0[0], m0[1], m0[2], m0[3]);
  *(float4*)(ob + 1 * PIX) = make_float4(d0[0], d0[1], d0[2], d0[3]);
  *(float4*)(ob + 2 * PIX) = make_float4(m1[0], m1[1], m1[2], m1[3]);
  *(float4*)(ob + 3 * PIX) = make_float4(d1[0], d1[1], d1[2], d1[3]);
  *(float4*)(ob + 4 * PIX) = make_float4(m2[0], m2[1], m2[2], m2[3]);
  *(float4*)(ob + 5 * PIX) = make_float4(d2[0], d2[1], d2[2], d2[3]);
}

// ---------------------------------------------------------------------------
// K1: conv1 (6 image channels + uniform-channel constant) + BN + ReLU +
// 2x2 maxpool -> x1h channel-last f16 [b][15][16][64].
// ---------------------------------------------------------------------------
__global__ __launch_bounds__(256) void k1_conv1(
    const float* __restrict__ img6, const float* __restrict__ scal,
    const float* __restrict__ wgt, const float* __restrict__ bias,
    const float* __restrict__ gam, const float* __restrict__ bet,
    const float* __restrict__ mu, const float* __restrict__ var,
    _Float16* __restrict__ x1h)
{
  __shared__ float s_img[6 * 1024];
  const int b = blockIdx.x, t = threadIdx.x, lane = t & 63, wave = t >> 6;
  const float* src = img6 + (size_t)b * 6144;
  for (int i = t; i < 1536; i += 256)
    ((float4*)s_img)[i] = ((const float4*)src)[i];

  const int oc = lane;
  const float* wp = wgt + oc * 126;
  float cst = 0.f;
  {
    const int uch[8] = {0, 1, 8, 9, 10, 11, 12, 13};
    const float* sp = scal + b * 8;
    #pragma unroll
    for (int u = 0; u < 8; ++u) {
      float s = 0.f;
      #pragma unroll
      for (int k = 0; k < 9; ++k) s += wp[uch[u] * 9 + k];
      cst += s * sp[u];
    }
  }
  float scv = gam[oc] * rsqrtf(var[oc] + EPSF);
  float shv = (bias[oc] - mu[oc]) * scv + bet[oc];
  __syncthreads();

  const int npr = (wave == 3) ? 3 : 4;
  for (int q = 0; q < 4; ++q) {
    if (q < npr) {
      const int pr = wave * 4 + q;
      const int r0 = pr * 2;
      float a0[30], a1[30];
      #pragma unroll
      for (int c = 0; c < 30; ++c) { a0[c] = 0.f; a1[c] = 0.f; }
      #pragma unroll 1
      for (int ci = 0; ci < 6; ++ci) {
        float cw[9];
        {
          const float4* wv = (const float4*)(wp + 18 + ci * 9);
          float4 w0 = wv[0], w1 = wv[1];
          cw[0]=w0.x; cw[1]=w0.y; cw[2]=w0.z; cw[3]=w0.w;
          cw[4]=w1.x; cw[5]=w1.y; cw[6]=w1.z; cw[7]=w1.w;
          cw[8]=wp[18 + ci * 9 + 8];
        }
        #pragma unroll
        for (int wr = 0; wr < 4; ++wr) {
          float rr[32];
          const float4* rp = (const float4*)(s_img + ci * 1024 + (r0 + wr) * 32);
          #pragma unroll
          for (int j = 0; j < 8; ++j) {
            float4 v = rp[j];
            rr[4*j] = v.x; rr[4*j+1] = v.y; rr[4*j+2] = v.z; rr[4*j+3] = v.w;
          }
          if (wr < 3) {
            #pragma unroll
            for (int col = 0; col < 30; ++col)
              #pragma unroll
              for (int kc = 0; kc < 3; ++kc)
                a0[col] = fmaf(cw[wr * 3 + kc], rr[col + kc], a0[col]);
          }
          if (wr >= 1) {
            #pragma unroll
            for (int col = 0; col < 30; ++col)
              #pragma unroll
              for (int kc = 0; kc < 3; ++kc)
                a1[col] = fmaf(cw[(wr - 1) * 3 + kc], rr[col + kc], a1[col]);
          }
        }
      }
      #pragma unroll
      for (int pc = 0; pc < 15; ++pc) {
        float m = fmaxf(fmaxf(a0[2*pc], a0[2*pc+1]), fmaxf(a1[2*pc], a1[2*pc+1]));
        float y = fmaxf(scv * (m + cst) + shv, 0.f);
        // channel-last f16: [b][pr][pc][oc]; lane=oc -> coalesced 128B store
        x1h[((((size_t)b * 15 + pr) * 16) + pc) * 64 + oc] = (_Float16)y;
      }
    }
  }
}

// ---------------------------------------------------------------------------
// K2/K3: 3x3 conv via MFMA implicit GEMM, f16 in / f32 acc.
// GEMM per kr-shift: D[oc][pix] += sum_{k=(kc,ci)} W[oc][k] * X[pix+(kr,kc)][ci]
// A-frag: lane m=lane&15 (oc), k=q*8+j  (from wrep [kr][oc][192], direct 16B)
// B-frag: lane n=lane&15 (pix), k=q*8+j (one ds_read_b128, LDS pixel stride 72)
// D: col=lane&15 (pix), row=q*4+reg (oc)
// ---------------------------------------------------------------------------
template<int IH, int OW, int NT>
__global__ __launch_bounds__(256, 3) void k_conv_mfma(
    const _Float16* __restrict__ xin, const _Float16* __restrict__ wrep,
    const float* __restrict__ bias, const float* __restrict__ gam,
    const float* __restrict__ bet, const float* __restrict__ mu,
    const float* __restrict__ var, _Float16* __restrict__ xout)
{
  constexpr int NPIX = OW * OW;
  constexpr int NIN = IH * 16;             // input pixels incl. padded cols
  __shared__ _Float16 s_in[NIN * 72 + 8];  // pixel stride 72 f16 (bank +4)
  const int b = blockIdx.x, t = threadIdx.x;
  const int lane = t & 63, wave = t >> 6;
  const int n16 = lane & 15, q = lane >> 4;

  // stage global [pix][64] f16 -> LDS [pix][72], 16B groups
  {
    const half8_t* src = (const half8_t*)(xin + (size_t)b * NIN * 64);
    half8_t* dst = (half8_t*)s_in;
    for (int g = t; g < NIN * 8; g += 256) {
      int pix = g >> 3, cib = g & 7;
      dst[pix * 9 + cib] = src[g];
    }
  }

  // per-lane output pixel bases (clamped for pad lanes)
  int base72[NT];
  #pragma unroll
  for (int nt = 0; nt < NT; ++nt) {
    int p = nt * 16 + n16;
    int pe = (p < NPIX) ? p : (NPIX - 1);
    int r = pe / OW, c = pe - r * OW;
    base72[nt] = (r * 16 + c) * 72;
  }

  float4_t acc[NT];
  #pragma unroll
  for (int nt = 0; nt < NT; ++nt) acc[nt] = (float4_t){0.f, 0.f, 0.f, 0.f};

  const int ocA = wave * 16 + n16;
  __syncthreads();

  #pragma unroll 1
  for (int kr = 0; kr < 3; ++kr) {
    half8_t af[6];
    const half8_t* wp = (const half8_t*)(wrep + (size_t)(kr * 64 + ocA) * 192 + q * 8);
    #pragma unroll
    for (int ks = 0; ks < 6; ++ks) af[ks] = wp[ks * 4];
    const int krbase = kr * (16 * 72);
    #pragma unroll
    for (int ks = 0; ks < 6; ++ks) {
      const int k0 = ks * 32 + q * 8;
      const int kadd = krbase + (k0 >> 6) * 72 + (k0 & 63);
      #pragma unroll
      for (int nt = 0; nt < NT; ++nt) {
        half8_t bf = *(const half8_t*)(s_in + base72[nt] + kadd);
        acc[nt] = __builtin_amdgcn_mfma_f32_16x16x32_f16(af[ks], bf, acc[nt], 0, 0, 0);
      }
    }
  }

  // epilogue: BN + ReLU, store channel-last f16 [b][OW][16][64]
  const int ocb = wave * 16 + q * 4;
  float scv[4], shv[4];
  #pragma unroll
  for (int rg = 0; rg < 4; ++rg) {
    int o = ocb + rg;
    float s = gam[o] * rsqrtf(var[o] + EPSF);
    scv[rg] = s;
    shv[rg] = (bias[o] - mu[o]) * s + bet[o];
  }
  #pragma unroll
  for (int nt = 0; nt < NT; ++nt) {
    int p = nt * 16 + n16;
    if (p < NPIX) {
      int r = p / OW, c = p - r * OW;
      half4_t v;
      #pragma unroll
      for (int rg = 0; rg < 4; ++rg)
        v[rg] = (_Float16)fmaxf(acc[nt][rg] * scv[rg] + shv[rg], 0.f);
      *(half4_t*)(xout + (((size_t)b * OW + r) * 16 + c) * 64 + ocb) = v;
    }
  }
}

// ---------------------------------------------------------------------------
// K4: conv4 (64->1) + bias + global max. x3h f16 [b][11][16][64].
// ---------------------------------------------------------------------------
__global__ __launch_bounds__(128) void k4_conv4max(
    const _Float16* __restrict__ x3, const float* __restrict__ w4,
    const float* __restrict__ b4, float* __restrict__ out)
{
  __shared__ _Float16 s_in[11 * 16 * 72 + 8];   // pixel stride 72
  __shared__ float s_w[9][64];                  // transposed weights
  __shared__ float s_red[2];
  const int b = blockIdx.x, t = threadIdx.x;
  {
    const half8_t* src = (const half8_t*)(x3 + (size_t)b * 11 * 16 * 64);
    half8_t* dst = (half8_t*)s_in;
    for (int g = t; g < 11 * 16 * 8; g += 128) {
      int pix = g >> 3, cib = g & 7;
      dst[pix * 9 + cib] = src[g];
    }
  }
  for (int i = t; i < 576; i += 128) {
    int ci = i / 9, k = i - ci * 9;
    s_w[k][ci] = w4[i];
  }
  __syncthreads();
  float val = -INFINITY;
  if (t < 81) {
    const int r = t / 9, c = t - (t / 9) * 9;
    float acc = 0.f;
    #pragma unroll
    for (int kr = 0; kr < 3; ++kr)
      #pragma unroll
      for (int kc = 0; kc < 3; ++kc) {
        const _Float16* ip = s_in + ((r + kr) * 16 + (c + kc)) * 72;
        const float* wk = s_w[kr * 3 + kc];
        #pragma unroll
        for (int cig = 0; cig < 8; ++cig) {
          half8_t x = *(const half8_t*)(ip + cig * 8);
          #pragma unroll
          for (int j = 0; j < 8; ++j)
            acc = fmaf((float)x[j], wk[cig * 8 + j], acc);
        }
      }
    val = acc;
  }
  #pragma unroll
  for (int off = 32; off > 0; off >>= 1)
    val = fmaxf(val, __shfl_down(val, off, 64));
  if ((t & 63) == 0) s_red[t >> 6] = val;
  __syncthreads();
  if (t == 0) out[b] = fmaxf(s_red[0], s_red[1]) + b4[0];
}

// ---------------------------------------------------------------------------
extern "C" void kernel_launch(void* const* d_in, const int* in_sizes, int n_in,
                              void* d_out, int out_size, void* d_ws, size_t ws_size,
                              hipStream_t stream) {
  const float* ts   = (const float*)d_in[0];
  const float* ptm  = (const float*)d_in[1];
  const float* pmt  = (const float*)d_in[2];
  const float* piou = (const float*)d_in[3];
  const int*   mask = (const int*)d_in[4];
  const float* c1w = (const float*)d_in[5];
  const float* c1b = (const float*)d_in[6];
  const float* g1  = (const float*)d_in[7];
  const float* b1  = (const float*)d_in[8];
  const float* m1  = (const float*)d_in[9];
  const float* v1  = (const float*)d_in[10];
  const float* c2w = (const float*)d_in[11];
  const float* c2b = (const float*)d_in[12];
  const float* g2  = (const float*)d_in[13];
  const float* b2  = (const float*)d_in[14];
  const float* m2  = (const float*)d_in[15];
  const float* v2  = (const float*)d_in[16];
  const float* c3w = (const float*)d_in[17];
  const float* c3b = (const float*)d_in[18];
  const float* g3  = (const float*)d_in[19];
  const float* b3  = (const float*)d_in[20];
  const float* m3  = (const float*)d_in[21];
  const float* v3  = (const float*)d_in[22];
  const float* c4w = (const float*)d_in[23];
  const float* c4b = (const float*)d_in[24];

  char* ws = (char*)d_ws;
  float*     img6  = (float*)ws;
  float*     scal  = (float*)(ws + OFF_SCAL);
  _Float16*  x1h   = (_Float16*)(ws + OFF_X1H);
  _Float16*  x2h   = (_Float16*)(ws + OFF_X2H);
  _Float16*  x3h   = (_Float16*)(ws + OFF_X3H);
  _Float16*  w2rep = (_Float16*)(ws + OFF_W2R);
  _Float16*  w3rep = (_Float16*)(ws + OFF_W3R);

  k_repack<<<144, 256, 0, stream>>>(c2w, w2rep);
  k_repack<<<144, 256, 0, stream>>>(c3w, w3rep);
  k0_stats<<<NFB, 256, 0, stream>>>(ts, ptm, pmt, piou, mask, img6, scal);
  k1_conv1<<<NFB, 256, 0, stream>>>(img6, scal, c1w, c1b, g1, b1, m1, v1, x1h);
  k_conv_mfma<15, 13, 11><<<NFB, 256, 0, stream>>>(x1h, w2rep, c2b, g2, b2, m2, v2, x2h);
  k_conv_mfma<13, 11, 8><<<NFB, 256, 0, stream>>>(x2h, w3rep, c3b, g3, b3, m3, v3, x3h);
  k4_conv4max<<<NFB, 128, 0, stream>>>(x3h, c4w, c4b, (float*)d_out);
}

// Round 5
// 295.833 us; speedup vs baseline: 4.3090x; 1.0758x over previous
//
#include <hip/hip_runtime.h>
#include <math.h>

#define NFB  512     // B = nf*ns
#define NMEM 30
#define PIX  1024    // 32*32
#define EPSF 1e-5f

typedef _Float16 half8_t __attribute__((ext_vector_type(8)));
typedef _Float16 half4_t __attribute__((ext_vector_type(4)));
typedef float float4_t __attribute__((ext_vector_type(4)));

// workspace layout (byte offsets):
// img6   (fp32, 512*6*1024)   @ 0           size 12,582,912
// scal12 (fp32, 512*12)       @ 12,582,912  size 24,576
// pmax   (fp32, 512*30)       @ 12,607,488  size 61,440
// wpair  (float2, 512*30)     @ 12,668,928  size 122,880
// x1h    (f16, 512*15*16*64)  @ 12,791,808  size 15,728,640
// x2h    (f16, 512*13*16*64)  @ 28,520,448  size 13,631,488
// x3h    (f16, 512*11*16*64)  @ 42,151,936  size 11,534,336
// w2rep  (f16, 3*64*192)      @ 53,686,272  size 73,728
// w3rep  (f16, 3*64*192)      @ 53,760,000  size 73,728   (end 53,833,728)
#define OFF_SCAL 12582912
#define OFF_PMAX 12607488
#define OFF_WPAIR 12668928
#define OFF_X1H  12791808
#define OFF_X2H  28520448
#define OFF_X3H  42151936
#define OFF_W2R  53686272
#define OFF_W3R  53760000

// ---------------------------------------------------------------------------
// repack conv weights [oc][ci][3][3] fp32 -> [kr][oc][kc*64+ci] f16
// ---------------------------------------------------------------------------
__global__ __launch_bounds__(256) void k_repack(
    const float* __restrict__ w, _Float16* __restrict__ wr)
{
  int i = blockIdx.x * 256 + threadIdx.x;     // over 3*64*192 = 36864
  if (i < 36864) {
    int kr = i / 12288;
    int rem = i - kr * 12288;
    int oc = rem / 192;
    int k = rem - oc * 192;
    int kc = k >> 6, ci = k & 63;
    wr[i] = (_Float16)w[((oc * 64 + ci) * 3 + kr) * 3 + kc];
  }
}

// ---------------------------------------------------------------------------
// kA: per-(b,m) spatial max of ptm. One wave per (b,m); 4 indep float4/lane.
// ---------------------------------------------------------------------------
__global__ __launch_bounds__(256) void kA_ptm_max(
    const float* __restrict__ ptm, float* __restrict__ pmax)
{
  const int t = threadIdx.x, lane = t & 63, wave = t >> 6;
  const int w = blockIdx.x * 4 + wave;        // 0 .. 512*30-1
  const float* p = ptm + (size_t)w * PIX;
  float4 v0 = *(const float4*)(p + lane * 4);
  float4 v1 = *(const float4*)(p + lane * 4 + 256);
  float4 v2 = *(const float4*)(p + lane * 4 + 512);
  float4 v3 = *(const float4*)(p + lane * 4 + 768);
  float mx = fmaxf(fmaxf(fmaxf(v0.x, v0.y), fmaxf(v0.z, v0.w)),
                   fmaxf(fmaxf(v1.x, v1.y), fmaxf(v1.z, v1.w)));
  mx = fmaxf(mx, fmaxf(fmaxf(fmaxf(v2.x, v2.y), fmaxf(v2.z, v2.w)),
                       fmaxf(fmaxf(v3.x, v3.y), fmaxf(v3.z, v3.w))));
  #pragma unroll
  for (int off = 32; off > 0; off >>= 1)
    mx = fmaxf(mx, __shfl_down(mx, off, 64));
  if (lane == 0) pmax[w] = mx;
}

// ---------------------------------------------------------------------------
// kB: per-b scalars. ts max (all 256 threads) + mask cumsum + pmax stats (t0).
// Writes scal12[b][12] = {max_ts, piou, m_mm, s_mm, m_gm, s_gm, m_om, s_om,
//                         cm, cg, co, 0} and wpair[b][30] = {wm, wo}.
// ---------------------------------------------------------------------------
__global__ __launch_bounds__(256) void kB_scal(
    const float* __restrict__ ts, const float* __restrict__ piou,
    const int* __restrict__ mask, const float* __restrict__ pmax,
    float* __restrict__ scal12, float2* __restrict__ wpair)
{
  const int b = blockIdx.x, t = threadIdx.x, lane = t & 63, wave = t >> 6;
  __shared__ float s_red[4];
  {
    float4 v = ((const float4*)(ts + (size_t)b * PIX))[t];
    float mx = fmaxf(fmaxf(v.x, v.y), fmaxf(v.z, v.w));
    #pragma unroll
    for (int off = 32; off > 0; off >>= 1)
      mx = fmaxf(mx, __shfl_down(mx, off, 64));
    if (lane == 0) s_red[wave] = mx;
  }
  __syncthreads();
  if (t == 0) {
    float maxts = fmaxf(fmaxf(s_red[0], s_red[1]), fmaxf(s_red[2], s_red[3]));
    float wm[NMEM], wo[NMEM];
    float cum = 0.f, cm = 0.f, cg = 0.f, co = 0.f;
    #pragma unroll
    for (int m = 0; m < NMEM; ++m) {
      float f  = (mask[b * NMEM + m] != 0) ? 1.f : 0.f;
      float gg = (cum < 15.f) ? f : 0.f;
      float oo = f - gg;
      cum += f;
      wm[m] = f; wo[m] = oo;
      cm += f; cg += gg; co += oo;
    }
    const float* px = pmax + b * NMEM;
    float sm = 0, sm2 = 0, sg = 0, sg2 = 0, so = 0, so2 = 0;
    #pragma unroll
    for (int m = 0; m < NMEM; ++m) {
      float x = px[m];
      float gg = wm[m] - wo[m];
      sm += wm[m] * x;  sm2 += wm[m] * x * x;
      sg += gg * x;     sg2 += gg * x * x;
      so += wo[m] * x;  so2 += wo[m] * x * x;
      wpair[b * NMEM + m] = make_float2(wm[m], wo[m]);
    }
    float a = sm / cm, g = sg / cg, o = so / co;
    float* sp = scal12 + b * 12;
    sp[0] = maxts; sp[1] = piou[b];
    sp[2] = a; sp[3] = sqrtf(fmaxf(sm2 / cm - a * a, 0.f));
    sp[4] = g; sp[5] = sqrtf(fmaxf(sg2 / cg - g * g, 0.f));
    sp[6] = o; sp[7] = sqrtf(fmaxf(so2 / co - o * o, 0.f));
    sp[8] = cm; sp[9] = cg; sp[10] = co; sp[11] = 0.f;
  }
}

// ---------------------------------------------------------------------------
// kC: per-pixel pmt masked stats -> img6 (B,6,32,32 fp32).
// Thread owns 4 consecutive pixels; m-loop in two 15-m halves, each batched
// 5 float4-loads deep for memory-level parallelism (gth term compile-time).
// ---------------------------------------------------------------------------
__global__ __launch_bounds__(256) void kC_pmt_stats(
    const float* __restrict__ pmt, const float2* __restrict__ wpair,
    const float* __restrict__ scal12, float* __restrict__ img6)
{
  const int b = blockIdx.x, t = threadIdx.x;
  __shared__ float s_wm[NMEM], s_wo[NMEM];
  if (t < NMEM) {
    float2 wv = wpair[b * NMEM + t];
    s_wm[t] = wv.x; s_wo[t] = wv.y;
  }
  __syncthreads();
  const float cm = scal12[b * 12 + 8];
  const float co = scal12[b * 12 + 10];
  const int p0 = t * 4;
  const float* pb = pmt + (size_t)b * NMEM * PIX + p0;

  float sA[4] = {0,0,0,0}, qA[4] = {0,0,0,0};
  float sG[4] = {0,0,0,0}, qG[4] = {0,0,0,0};
  float sO[4] = {0,0,0,0}, qO[4] = {0,0,0,0};

  // first half: m in [0,15) — all gth members
  #pragma unroll 1
  for (int mb = 0; mb < 15; mb += 5) {
    float4 v[5];
    #pragma unroll
    for (int j = 0; j < 5; ++j) v[j] = *(const float4*)(pb + (size_t)(mb + j) * PIX);
    #pragma unroll
    for (int j = 0; j < 5; ++j) {
      float wm = s_wm[mb + j], wo = s_wo[mb + j];
      float xv[4] = {v[j].x, v[j].y, v[j].z, v[j].w};
      #pragma unroll
      for (int k = 0; k < 4; ++k) {
        float x = xv[k];
        sA[k] = fmaf(wm, x, sA[k]); qA[k] = fmaf(wm * x, x, qA[k]);
        sO[k] = fmaf(wo, x, sO[k]); qO[k] = fmaf(wo * x, x, qO[k]);
        sG[k] += x; qG[k] = fmaf(x, x, qG[k]);
      }
    }
  }
  // second half: m in [15,30) — no gth
  #pragma unroll 1
  for (int mb = 15; mb < 30; mb += 5) {
    float4 v[5];
    #pragma unroll
    for (int j = 0; j < 5; ++j) v[j] = *(const float4*)(pb + (size_t)(mb + j) * PIX);
    #pragma unroll
    for (int j = 0; j < 5; ++j) {
      float wm = s_wm[mb + j], wo = s_wo[mb + j];
      float xv[4] = {v[j].x, v[j].y, v[j].z, v[j].w};
      #pragma unroll
      for (int k = 0; k < 4; ++k) {
        float x = xv[k];
        sA[k] = fmaf(wm, x, sA[k]); qA[k] = fmaf(wm * x, x, qA[k]);
        sO[k] = fmaf(wo, x, sO[k]); qO[k] = fmaf(wo * x, x, qO[k]);
      }
    }
  }

  float* ob = img6 + (size_t)b * 6144 + p0;
  float m0[4], d0[4], m1[4], d1[4], m2[4], d2[4];
  #pragma unroll
  for (int j = 0; j < 4; ++j) {
    m0[j] = sA[j] / cm;   d0[j] = sqrtf(fmaxf(qA[j] / cm - m0[j] * m0[j], 0.f));
    m1[j] = sG[j] / 15.f; d1[j] = sqrtf(fmaxf(qG[j] / 15.f - m1[j] * m1[j], 0.f));
    m2[j] = sO[j] / co;   d2[j] = sqrtf(fmaxf(qO[j] / co - m2[j] * m2[j], 0.f));
  }
  *(float4*)(ob + 0 * PIX) = make_float4(m0[0], m0[1], m0[2], m0[3]);
  *(float4*)(ob + 1 * PIX) = make_float4(d0[0], d0[1], d0[2], d0[3]);
  *(float4*)(ob + 2 * PIX) = make_float4(m1[0], m1[1], m1[2], m1[3]);
  *(float4*)(ob + 3 * PIX) = make_float4(d1[0], d1[1], d1[2], d1[3]);
  *(float4*)(ob + 4 * PIX) = make_float4(m2[0], m2[1], m2[2], m2[3]);
  *(float4*)(ob + 5 * PIX) = make_float4(d2[0], d2[1], d2[2], d2[3]);
}

// ---------------------------------------------------------------------------
// K1: conv1 (6 image channels + uniform-channel constant) + BN + ReLU +
// 2x2 maxpool -> x1h channel-last f16 [b][15][16][64].
// ---------------------------------------------------------------------------
__global__ __launch_bounds__(256) void k1_conv1(
    const float* __restrict__ img6, const float* __restrict__ scal12,
    const float* __restrict__ wgt, const float* __restrict__ bias,
    const float* __restrict__ gam, const float* __restrict__ bet,
    const float* __restrict__ mu, const float* __restrict__ var,
    _Float16* __restrict__ x1h)
{
  __shared__ float s_img[6 * 1024];
  const int b = blockIdx.x, t = threadIdx.x, lane = t & 63, wave = t >> 6;
  const float* src = img6 + (size_t)b * 6144;
  for (int i = t; i < 1536; i += 256)
    ((float4*)s_img)[i] = ((const float4*)src)[i];

  const int oc = lane;
  const float* wp = wgt + oc * 126;
  float cst = 0.f;
  {
    const int uch[8] = {0, 1, 8, 9, 10, 11, 12, 13};
    const float* sp = scal12 + b * 12;
    #pragma unroll
    for (int u = 0; u < 8; ++u) {
      float s = 0.f;
      #pragma unroll
      for (int k = 0; k < 9; ++k) s += wp[uch[u] * 9 + k];
      cst += s * sp[u];
    }
  }
  float scv = gam[oc] * rsqrtf(var[oc] + EPSF);
  float shv = (bias[oc] - mu[oc]) * scv + bet[oc];
  __syncthreads();

  const int npr = (wave == 3) ? 3 : 4;
  for (int q = 0; q < 4; ++q) {
    if (q < npr) {
      const int pr = wave * 4 + q;
      const int r0 = pr * 2;
      float a0[30], a1[30];
      #pragma unroll
      for (int c = 0; c < 30; ++c) { a0[c] = 0.f; a1[c] = 0.f; }
      #pragma unroll 1
      for (int ci = 0; ci < 6; ++ci) {
        float cw[9];
        {
          const float4* wv = (const float4*)(wp + 18 + ci * 9);
          float4 w0 = wv[0], w1 = wv[1];
          cw[0]=w0.x; cw[1]=w0.y; cw[2]=w0.z; cw[3]=w0.w;
          cw[4]=w1.x; cw[5]=w1.y; cw[6]=w1.z; cw[7]=w1.w;
          cw[8]=wp[18 + ci * 9 + 8];
        }
        #pragma unroll
        for (int wr = 0; wr < 4; ++wr) {
          float rr[32];
          const float4* rp = (const float4*)(s_img + ci * 1024 + (r0 + wr) * 32);
          #pragma unroll
          for (int j = 0; j < 8; ++j) {
            float4 v = rp[j];
            rr[4*j] = v.x; rr[4*j+1] = v.y; rr[4*j+2] = v.z; rr[4*j+3] = v.w;
          }
          if (wr < 3) {
            #pragma unroll
            for (int col = 0; col < 30; ++col)
              #pragma unroll
              for (int kc = 0; kc < 3; ++kc)
                a0[col] = fmaf(cw[wr * 3 + kc], rr[col + kc], a0[col]);
          }
          if (wr >= 1) {
            #pragma unroll
            for (int col = 0; col < 30; ++col)
              #pragma unroll
              for (int kc = 0; kc < 3; ++kc)
                a1[col] = fmaf(cw[(wr - 1) * 3 + kc], rr[col + kc], a1[col]);
          }
        }
      }
      #pragma unroll
      for (int pc = 0; pc < 15; ++pc) {
        float m = fmaxf(fmaxf(a0[2*pc], a0[2*pc+1]), fmaxf(a1[2*pc], a1[2*pc+1]));
        float y = fmaxf(scv * (m + cst) + shv, 0.f);
        x1h[((((size_t)b * 15 + pr) * 16) + pc) * 64 + oc] = (_Float16)y;
      }
    }
  }
}

// ---------------------------------------------------------------------------
// K2/K3: 3x3 conv via MFMA implicit GEMM, f16 in / f32 acc.
// ---------------------------------------------------------------------------
template<int IH, int OW, int NT>
__global__ __launch_bounds__(256, 3) void k_conv_mfma(
    const _Float16* __restrict__ xin, const _Float16* __restrict__ wrep,
    const float* __restrict__ bias, const float* __restrict__ gam,
    const float* __restrict__ bet, const float* __restrict__ mu,
    const float* __restrict__ var, _Float16* __restrict__ xout)
{
  constexpr int NPIX = OW * OW;
  constexpr int NIN = IH * 16;
  __shared__ _Float16 s_in[NIN * 72 + 8];
  const int b = blockIdx.x, t = threadIdx.x;
  const int lane = t & 63, wave = t >> 6;
  const int n16 = lane & 15, q = lane >> 4;

  {
    const half8_t* src = (const half8_t*)(xin + (size_t)b * NIN * 64);
    half8_t* dst = (half8_t*)s_in;
    for (int g = t; g < NIN * 8; g += 256) {
      int pix = g >> 3, cib = g & 7;
      dst[pix * 9 + cib] = src[g];
    }
  }

  int base72[NT];
  #pragma unroll
  for (int nt = 0; nt < NT; ++nt) {
    int p = nt * 16 + n16;
    int pe = (p < NPIX) ? p : (NPIX - 1);
    int r = pe / OW, c = pe - r * OW;
    base72[nt] = (r * 16 + c) * 72;
  }

  float4_t acc[NT];
  #pragma unroll
  for (int nt = 0; nt < NT; ++nt) acc[nt] = (float4_t){0.f, 0.f, 0.f, 0.f};

  const int ocA = wave * 16 + n16;
  __syncthreads();

  #pragma unroll 1
  for (int kr = 0; kr < 3; ++kr) {
    half8_t af[6];
    const half8_t* wp = (const half8_t*)(wrep + (size_t)(kr * 64 + ocA) * 192 + q * 8);
    #pragma unroll
    for (int ks = 0; ks < 6; ++ks) af[ks] = wp[ks * 4];
    const int krbase = kr * (16 * 72);
    #pragma unroll
    for (int ks = 0; ks < 6; ++ks) {
      const int k0 = ks * 32 + q * 8;
      const int kadd = krbase + (k0 >> 6) * 72 + (k0 & 63);
      #pragma unroll
      for (int nt = 0; nt < NT; ++nt) {
        half8_t bf = *(const half8_t*)(s_in + base72[nt] + kadd);
        acc[nt] = __builtin_amdgcn_mfma_f32_16x16x32_f16(af[ks], bf, acc[nt], 0, 0, 0);
      }
    }
  }

  const int ocb = wave * 16 + q * 4;
  float scv[4], shv[4];
  #pragma unroll
  for (int rg = 0; rg < 4; ++rg) {
    int o = ocb + rg;
    float s = gam[o] * rsqrtf(var[o] + EPSF);
    scv[rg] = s;
    shv[rg] = (bias[o] - mu[o]) * s + bet[o];
  }
  #pragma unroll
  for (int nt = 0; nt < NT; ++nt) {
    int p = nt * 16 + n16;
    if (p < NPIX) {
      int r = p / OW, c = p - r * OW;
      half4_t v;
      #pragma unroll
      for (int rg = 0; rg < 4; ++rg)
        v[rg] = (_Float16)fmaxf(acc[nt][rg] * scv[rg] + shv[rg], 0.f);
      *(half4_t*)(xout + (((size_t)b * OW + r) * 16 + c) * 64 + ocb) = v;
    }
  }
}

// ---------------------------------------------------------------------------
// K4: conv4 (64->1) + bias + global max. x3h f16 [b][11][16][64].
// ---------------------------------------------------------------------------
__global__ __launch_bounds__(128) void k4_conv4max(
    const _Float16* __restrict__ x3, const float* __restrict__ w4,
    const float* __restrict__ b4, float* __restrict__ out)
{
  __shared__ _Float16 s_in[11 * 16 * 72 + 8];
  __shared__ float s_w[9][64];
  __shared__ float s_red[2];
  const int b = blockIdx.x, t = threadIdx.x;
  {
    const half8_t* src = (const half8_t*)(x3 + (size_t)b * 11 * 16 * 64);
    half8_t* dst = (half8_t*)s_in;
    for (int g = t; g < 11 * 16 * 8; g += 128) {
      int pix = g >> 3, cib = g & 7;
      dst[pix * 9 + cib] = src[g];
    }
  }
  for (int i = t; i < 576; i += 128) {
    int ci = i / 9, k = i - ci * 9;
    s_w[k][ci] = w4[i];
  }
  __syncthreads();
  float val = -INFINITY;
  if (t < 81) {
    const int r = t / 9, c = t - (t / 9) * 9;
    float acc = 0.f;
    #pragma unroll
    for (int kr = 0; kr < 3; ++kr)
      #pragma unroll
      for (int kc = 0; kc < 3; ++kc) {
        const _Float16* ip = s_in + ((r + kr) * 16 + (c + kc)) * 72;
        const float* wk = s_w[kr * 3 + kc];
        #pragma unroll
        for (int cig = 0; cig < 8; ++cig) {
          half8_t x = *(const half8_t*)(ip + cig * 8);
          #pragma unroll
          for (int j = 0; j < 8; ++j)
            acc = fmaf((float)x[j], wk[cig * 8 + j], acc);
        }
      }
    val = acc;
  }
  #pragma unroll
  for (int off = 32; off > 0; off >>= 1)
    val = fmaxf(val, __shfl_down(val, off, 64));
  if ((t & 63) == 0) s_red[t >> 6] = val;
  __syncthreads();
  if (t == 0) out[b] = fmaxf(s_red[0], s_red[1]) + b4[0];
}

// ---------------------------------------------------------------------------
extern "C" void kernel_launch(void* const* d_in, const int* in_sizes, int n_in,
                              void* d_out, int out_size, void* d_ws, size_t ws_size,
                              hipStream_t stream) {
  const float* ts   = (const float*)d_in[0];
  const float* ptm  = (const float*)d_in[1];
  const float* pmt  = (const float*)d_in[2];
  const float* piou = (const float*)d_in[3];
  const int*   mask = (const int*)d_in[4];
  const float* c1w = (const float*)d_in[5];
  const float* c1b = (const float*)d_in[6];
  const float* g1  = (const float*)d_in[7];
  const float* b1  = (const float*)d_in[8];
  const float* m1  = (const float*)d_in[9];
  const float* v1  = (const float*)d_in[10];
  const float* c2w = (const float*)d_in[11];
  const float* c2b = (const float*)d_in[12];
  const float* g2  = (const float*)d_in[13];
  const float* b2  = (const float*)d_in[14];
  const float* m2  = (const float*)d_in[15];
  const float* v2  = (const float*)d_in[16];
  const float* c3w = (const float*)d_in[17];
  const float* c3b = (const float*)d_in[18];
  const float* g3  = (const float*)d_in[19];
  const float* b3  = (const float*)d_in[20];
  const float* m3  = (const float*)d_in[21];
  const float* v3  = (const float*)d_in[22];
  const float* c4w = (const float*)d_in[23];
  const float* c4b = (const float*)d_in[24];

  char* ws = (char*)d_ws;
  float*     img6   = (float*)ws;
  float*     scal12 = (float*)(ws + OFF_SCAL);
  float*     pmax   = (float*)(ws + OFF_PMAX);
  float2*    wpair  = (float2*)(ws + OFF_WPAIR);
  _Float16*  x1h    = (_Float16*)(ws + OFF_X1H);
  _Float16*  x2h    = (_Float16*)(ws + OFF_X2H);
  _Float16*  x3h    = (_Float16*)(ws + OFF_X3H);
  _Float16*  w2rep  = (_Float16*)(ws + OFF_W2R);
  _Float16*  w3rep  = (_Float16*)(ws + OFF_W3R);

  k_repack<<<144, 256, 0, stream>>>(c2w, w2rep);
  k_repack<<<144, 256, 0, stream>>>(c3w, w3rep);
  kA_ptm_max<<<NFB * NMEM / 4, 256, 0, stream>>>(ptm, pmax);
  kB_scal<<<NFB, 256, 0, stream>>>(ts, piou, mask, pmax, scal12, wpair);
  kC_pmt_stats<<<NFB, 256, 0, stream>>>(pmt, wpair, scal12, img6);
  k1_conv1<<<NFB, 256, 0, stream>>>(img6, scal12, c1w, c1b, g1, b1, m1, v1, x1h);
  k_conv_mfma<15, 13, 11><<<NFB, 256, 0, stream>>>(x1h, w2rep, c2b, g2, b2, m2, v2, x2h);
  k_conv_mfma<13, 11, 8><<<NFB, 256, 0, stream>>>(x2h, w3rep, c3b, g3, b3, m3, v3, x3h);
  k4_conv4max<<<NFB, 128, 0, stream>>>(x3h, c4w, c4b, (float*)d_out);
}

// Round 6
// 262.753 us; speedup vs baseline: 4.8515x; 1.1259x over previous
//
#include <hip/hip_runtime.h>
#include <math.h>

#define NFB  512     // B = nf*ns
#define NMEM 30
#define PIX  1024    // 32*32
#define EPSF 1e-5f

typedef _Float16 half8_t __attribute__((ext_vector_type(8)));
typedef _Float16 half4_t __attribute__((ext_vector_type(4)));
typedef float float4_t __attribute__((ext_vector_type(4)));

// workspace layout (byte offsets):
// img6h  (f16, 512*1024*8)    @ 0           size 8,388,608
// scal12 (fp32, 512*12)       @ 8,388,608   size 24,576
// pmax   (fp32, 512*30)       @ 8,413,184   size 61,440
// wpair  (float2, 512*30)     @ 8,474,624   size 122,880
// x1h    (f16, 512*15*16*64)  @ 8,597,504   size 15,728,640
// x2h    (f16, 512*13*16*64)  @ 24,326,144  size 13,631,488
// x3h    (f16, 512*11*16*64)  @ 37,957,632  size 11,534,336
// w2rep  (f16, 3*64*192)      @ 49,491,968  size 73,728
// w3rep  (f16, 3*64*192)      @ 49,565,696  size 73,728
// wr1    (f16, 3*64*32)       @ 49,639,424  size 12,288
// wsum1  (fp32, 64*8)         @ 49,651,712  size 2,048    (end 49,653,760)
#define OFF_SCAL  8388608
#define OFF_PMAX  8413184
#define OFF_WPAIR 8474624
#define OFF_X1H   8597504
#define OFF_X2H   24326144
#define OFF_X3H   37957632
#define OFF_W2R   49491968
#define OFF_W3R   49565696
#define OFF_WR1   49639424
#define OFF_WSUM1 49651712

// ---------------------------------------------------------------------------
// repack conv2/3 weights [oc][ci][3][3] fp32 -> [kr][oc][kc*64+ci] f16
// ---------------------------------------------------------------------------
__global__ __launch_bounds__(256) void k_repack(
    const float* __restrict__ w, _Float16* __restrict__ wr)
{
  int i = blockIdx.x * 256 + threadIdx.x;     // over 3*64*192 = 36864
  if (i < 36864) {
    int kr = i / 12288;
    int rem = i - kr * 12288;
    int oc = rem / 192;
    int k = rem - oc * 192;
    int kc = k >> 6, ci = k & 63;
    wr[i] = (_Float16)w[((oc * 64 + ci) * 3 + kr) * 3 + kc];
  }
}

// ---------------------------------------------------------------------------
// repack conv1 weights: wr1[kr][oc][kc*8+ci] f16 (image channels 2..7;
// k>=24 or ci>=6 zero) + wsum1[oc][u] = 3x3 tap-sum for the 8 uniform chans.
// ---------------------------------------------------------------------------
__global__ __launch_bounds__(256) void k_repack1(
    const float* __restrict__ w, _Float16* __restrict__ wr1,
    float* __restrict__ wsum1)
{
  int i = blockIdx.x * 256 + threadIdx.x;
  if (i < 6144) {
    int kr = i / 2048;          // 64*32
    int rem = i - kr * 2048;
    int oc = rem >> 5;
    int k = rem & 31;
    int kc = k >> 3, ci = k & 7;
    _Float16 v = (_Float16)0.f;
    if (kc < 3 && ci < 6)
      v = (_Float16)w[((oc * 14 + (2 + ci)) * 3 + kr) * 3 + kc];
    wr1[i] = v;
  } else if (i < 6144 + 512) {
    int j = i - 6144;
    int oc = j >> 3, u = j & 7;
    const int uch[8] = {0, 1, 8, 9, 10, 11, 12, 13};
    const float* wp = w + (oc * 14 + uch[u]) * 9;
    float s = 0.f;
    #pragma unroll
    for (int k = 0; k < 9; ++k) s += wp[k];
    wsum1[j] = s;
  }
}

// ---------------------------------------------------------------------------
// kA: per-(b,m) spatial max of ptm. One wave per (b,m); 4 indep float4/lane.
// ---------------------------------------------------------------------------
__global__ __launch_bounds__(256) void kA_ptm_max(
    const float* __restrict__ ptm, float* __restrict__ pmax)
{
  const int t = threadIdx.x, lane = t & 63, wave = t >> 6;
  const int w = blockIdx.x * 4 + wave;        // 0 .. 512*30-1
  const float* p = ptm + (size_t)w * PIX;
  float4 v0 = *(const float4*)(p + lane * 4);
  float4 v1 = *(const float4*)(p + lane * 4 + 256);
  float4 v2 = *(const float4*)(p + lane * 4 + 512);
  float4 v3 = *(const float4*)(p + lane * 4 + 768);
  float mx = fmaxf(fmaxf(fmaxf(v0.x, v0.y), fmaxf(v0.z, v0.w)),
                   fmaxf(fmaxf(v1.x, v1.y), fmaxf(v1.z, v1.w)));
  mx = fmaxf(mx, fmaxf(fmaxf(fmaxf(v2.x, v2.y), fmaxf(v2.z, v2.w)),
                       fmaxf(fmaxf(v3.x, v3.y), fmaxf(v3.z, v3.w))));
  #pragma unroll
  for (int off = 32; off > 0; off >>= 1)
    mx = fmaxf(mx, __shfl_down(mx, off, 64));
  if (lane == 0) pmax[w] = mx;
}

// ---------------------------------------------------------------------------
// kB: per-b scalars -> scal12[b][12], wpair[b][30].
// ---------------------------------------------------------------------------
__global__ __launch_bounds__(256) void kB_scal(
    const float* __restrict__ ts, const float* __restrict__ piou,
    const int* __restrict__ mask, const float* __restrict__ pmax,
    float* __restrict__ scal12, float2* __restrict__ wpair)
{
  const int b = blockIdx.x, t = threadIdx.x, lane = t & 63, wave = t >> 6;
  __shared__ float s_red[4];
  {
    float4 v = ((const float4*)(ts + (size_t)b * PIX))[t];
    float mx = fmaxf(fmaxf(v.x, v.y), fmaxf(v.z, v.w));
    #pragma unroll
    for (int off = 32; off > 0; off >>= 1)
      mx = fmaxf(mx, __shfl_down(mx, off, 64));
    if (lane == 0) s_red[wave] = mx;
  }
  __syncthreads();
  if (t == 0) {
    float maxts = fmaxf(fmaxf(s_red[0], s_red[1]), fmaxf(s_red[2], s_red[3]));
    float wm[NMEM], wo[NMEM];
    float cum = 0.f, cm = 0.f, cg = 0.f, co = 0.f;
    #pragma unroll
    for (int m = 0; m < NMEM; ++m) {
      float f  = (mask[b * NMEM + m] != 0) ? 1.f : 0.f;
      float gg = (cum < 15.f) ? f : 0.f;
      float oo = f - gg;
      cum += f;
      wm[m] = f; wo[m] = oo;
      cm += f; cg += gg; co += oo;
    }
    const float* px = pmax + b * NMEM;
    float sm = 0, sm2 = 0, sg = 0, sg2 = 0, so = 0, so2 = 0;
    #pragma unroll
    for (int m = 0; m < NMEM; ++m) {
      float x = px[m];
      float gg = wm[m] - wo[m];
      sm += wm[m] * x;  sm2 += wm[m] * x * x;
      sg += gg * x;     sg2 += gg * x * x;
      so += wo[m] * x;  so2 += wo[m] * x * x;
      wpair[b * NMEM + m] = make_float2(wm[m], wo[m]);
    }
    float a = sm / cm, g = sg / cg, o = so / co;
    float* sp = scal12 + b * 12;
    sp[0] = maxts; sp[1] = piou[b];
    sp[2] = a; sp[3] = sqrtf(fmaxf(sm2 / cm - a * a, 0.f));
    sp[4] = g; sp[5] = sqrtf(fmaxf(sg2 / cg - g * g, 0.f));
    sp[6] = o; sp[7] = sqrtf(fmaxf(so2 / co - o * o, 0.f));
    sp[8] = cm; sp[9] = cg; sp[10] = co; sp[11] = 0.f;
  }
}

// ---------------------------------------------------------------------------
// kC: per-pixel pmt masked stats -> img6h (B,1024,8) channel-last f16.
// ---------------------------------------------------------------------------
__global__ __launch_bounds__(256) void kC_pmt_stats(
    const float* __restrict__ pmt, const float2* __restrict__ wpair,
    const float* __restrict__ scal12, _Float16* __restrict__ img6h)
{
  const int b = blockIdx.x, t = threadIdx.x;
  __shared__ float s_wm[NMEM], s_wo[NMEM];
  if (t < NMEM) {
    float2 wv = wpair[b * NMEM + t];
    s_wm[t] = wv.x; s_wo[t] = wv.y;
  }
  __syncthreads();
  const float cm = scal12[b * 12 + 8];
  const float co = scal12[b * 12 + 10];
  const int p0 = t * 4;
  const float* pb = pmt + (size_t)b * NMEM * PIX + p0;

  float sA[4] = {0,0,0,0}, qA[4] = {0,0,0,0};
  float sG[4] = {0,0,0,0}, qG[4] = {0,0,0,0};
  float sO[4] = {0,0,0,0}, qO[4] = {0,0,0,0};

  #pragma unroll 1
  for (int mb = 0; mb < 15; mb += 5) {
    float4 v[5];
    #pragma unroll
    for (int j = 0; j < 5; ++j) v[j] = *(const float4*)(pb + (size_t)(mb + j) * PIX);
    #pragma unroll
    for (int j = 0; j < 5; ++j) {
      float wm = s_wm[mb + j], wo = s_wo[mb + j];
      float xv[4] = {v[j].x, v[j].y, v[j].z, v[j].w};
      #pragma unroll
      for (int k = 0; k < 4; ++k) {
        float x = xv[k];
        sA[k] = fmaf(wm, x, sA[k]); qA[k] = fmaf(wm * x, x, qA[k]);
        sO[k] = fmaf(wo, x, sO[k]); qO[k] = fmaf(wo * x, x, qO[k]);
        sG[k] += x; qG[k] = fmaf(x, x, qG[k]);
      }
    }
  }
  #pragma unroll 1
  for (int mb = 15; mb < 30; mb += 5) {
    float4 v[5];
    #pragma unroll
    for (int j = 0; j < 5; ++j) v[j] = *(const float4*)(pb + (size_t)(mb + j) * PIX);
    #pragma unroll
    for (int j = 0; j < 5; ++j) {
      float wm = s_wm[mb + j], wo = s_wo[mb + j];
      float xv[4] = {v[j].x, v[j].y, v[j].z, v[j].w};
      #pragma unroll
      for (int k = 0; k < 4; ++k) {
        float x = xv[k];
        sA[k] = fmaf(wm, x, sA[k]); qA[k] = fmaf(wm * x, x, qA[k]);
        sO[k] = fmaf(wo, x, sO[k]); qO[k] = fmaf(wo * x, x, qO[k]);
      }
    }
  }

  half8_t* ob = (half8_t*)(img6h + (size_t)b * 8192 + (size_t)p0 * 8);
  #pragma unroll
  for (int j = 0; j < 4; ++j) {
    float m0 = sA[j] / cm;   float d0 = sqrtf(fmaxf(qA[j] / cm - m0 * m0, 0.f));
    float m1 = sG[j] / 15.f; float d1 = sqrtf(fmaxf(qG[j] / 15.f - m1 * m1, 0.f));
    float m2 = sO[j] / co;   float d2 = sqrtf(fmaxf(qO[j] / co - m2 * m2, 0.f));
    half8_t v;
    v[0] = (_Float16)m0; v[1] = (_Float16)d0;
    v[2] = (_Float16)m1; v[3] = (_Float16)d1;
    v[4] = (_Float16)m2; v[5] = (_Float16)d2;
    v[6] = (_Float16)0.f; v[7] = (_Float16)0.f;
    ob[j] = v;
  }
}

// ---------------------------------------------------------------------------
// K1: conv1 via MFMA implicit GEMM + uniform-channel constant + BN + ReLU +
// 2x2 maxpool -> x1h channel-last f16 [b][15][16][64].
// A-frag: m=oc (wave*16+n16), k=q*8+j from wr1 [kr][oc][32]
// B-frag: n=conv-col pixel, k=q*8+j -> 16B at s_img[(pix+q)*8] (q=3 k-pad
//         reads garbage; annihilated by zero weights — tail zeroed for NaN)
// Pool: vertical in-lane (row accumulators), horizontal via shfl_xor(1).
// ---------------------------------------------------------------------------
__global__ __launch_bounds__(256) void k1_conv1_mfma(
    const _Float16* __restrict__ img6h, const float* __restrict__ scal12,
    const _Float16* __restrict__ wr1, const float* __restrict__ wsum1,
    const float* __restrict__ bias, const float* __restrict__ gam,
    const float* __restrict__ bet, const float* __restrict__ mu,
    const float* __restrict__ var, _Float16* __restrict__ x1h)
{
  __shared__ _Float16 s_img[1028 * 8];
  const int b = blockIdx.x, t = threadIdx.x, lane = t & 63, wave = t >> 6;
  const int n16 = lane & 15, q = lane >> 4;
  {
    const half8_t* src = (const half8_t*)(img6h + (size_t)b * 8192);
    half8_t* dst = (half8_t*)s_img;
    for (int i = t; i < 1024; i += 256) dst[i] = src[i];
    if (t < 4) {
      half8_t z = {(_Float16)0.f, (_Float16)0.f, (_Float16)0.f, (_Float16)0.f,
                   (_Float16)0.f, (_Float16)0.f, (_Float16)0.f, (_Float16)0.f};
      dst[1024 + t] = z;
    }
  }

  const int ocA = wave * 16 + n16;
  half8_t af[3];
  #pragma unroll
  for (int kr = 0; kr < 3; ++kr)
    af[kr] = *(const half8_t*)(wr1 + (kr * 64 + ocA) * 32 + q * 8);

  const int oc0 = wave * 16 + q * 4;
  float scv[4], shv[4], cst[4];
  {
    const float* sp = scal12 + b * 12;
    #pragma unroll
    for (int rg = 0; rg < 4; ++rg) {
      int oc = oc0 + rg;
      float s = gam[oc] * rsqrtf(var[oc] + EPSF);
      scv[rg] = s;
      shv[rg] = (bias[oc] - mu[oc]) * s + bet[oc];
      float c = 0.f;
      #pragma unroll
      for (int u = 0; u < 8; ++u) c = fmaf(wsum1[oc * 8 + u], sp[u], c);
      cst[rg] = c;
    }
  }
  __syncthreads();

  #pragma unroll 1
  for (int pr = 0; pr < 15; ++pr) {
    const int r0 = pr * 2;
    float4_t acc[2][2];
    #pragma unroll
    for (int row = 0; row < 2; ++row)
      #pragma unroll
      for (int tt = 0; tt < 2; ++tt)
        acc[row][tt] = (float4_t){0.f, 0.f, 0.f, 0.f};
    #pragma unroll
    for (int row = 0; row < 2; ++row) {
      #pragma unroll
      for (int kr = 0; kr < 3; ++kr) {
        const int ip = (r0 + row + kr) * 32 + n16 + q;
        #pragma unroll
        for (int tt = 0; tt < 2; ++tt) {
          half8_t bf = *(const half8_t*)(s_img + (ip + tt * 16) * 8);
          acc[row][tt] = __builtin_amdgcn_mfma_f32_16x16x32_f16(
              af[kr], bf, acc[row][tt], 0, 0, 0);
        }
      }
    }
    #pragma unroll
    for (int tt = 0; tt < 2; ++tt) {
      float mm[4];
      #pragma unroll
      for (int j = 0; j < 4; ++j) {
        float m = fmaxf(acc[0][tt][j], acc[1][tt][j]);
        mm[j] = fmaxf(m, __shfl_xor(m, 1, 64));
      }
      if ((n16 & 1) == 0) {
        int pc = tt * 8 + (n16 >> 1);
        half4_t v;
        if (pc < 15) {
          #pragma unroll
          for (int rg = 0; rg < 4; ++rg)
            v[rg] = (_Float16)fmaxf(scv[rg] * (mm[rg] + cst[rg]) + shv[rg], 0.f);
        } else {
          v[0] = (_Float16)0.f; v[1] = (_Float16)0.f;
          v[2] = (_Float16)0.f; v[3] = (_Float16)0.f;
        }
        *(half4_t*)(x1h + ((((size_t)b * 15 + pr) * 16) + pc) * 64 + oc0) = v;
      }
    }
  }
}

// ---------------------------------------------------------------------------
// K2/K3: 3x3 conv via MFMA implicit GEMM, f16 in / f32 acc.
// ---------------------------------------------------------------------------
template<int IH, int OW, int NT>
__global__ __launch_bounds__(256, 3) void k_conv_mfma(
    const _Float16* __restrict__ xin, const _Float16* __restrict__ wrep,
    const float* __restrict__ bias, const float* __restrict__ gam,
    const float* __restrict__ bet, const float* __restrict__ mu,
    const float* __restrict__ var, _Float16* __restrict__ xout)
{
  constexpr int NPIX = OW * OW;
  constexpr int NIN = IH * 16;
  __shared__ _Float16 s_in[NIN * 72 + 8];
  const int b = blockIdx.x, t = threadIdx.x;
  const int lane = t & 63, wave = t >> 6;
  const int n16 = lane & 15, q = lane >> 4;

  {
    const half8_t* src = (const half8_t*)(xin + (size_t)b * NIN * 64);
    half8_t* dst = (half8_t*)s_in;
    for (int g = t; g < NIN * 8; g += 256) {
      int pix = g >> 3, cib = g & 7;
      dst[pix * 9 + cib] = src[g];
    }
  }

  int base72[NT];
  #pragma unroll
  for (int nt = 0; nt < NT; ++nt) {
    int p = nt * 16 + n16;
    int pe = (p < NPIX) ? p : (NPIX - 1);
    int r = pe / OW, c = pe - r * OW;
    base72[nt] = (r * 16 + c) * 72;
  }

  float4_t acc[NT];
  #pragma unroll
  for (int nt = 0; nt < NT; ++nt) acc[nt] = (float4_t){0.f, 0.f, 0.f, 0.f};

  const int ocA = wave * 16 + n16;
  __syncthreads();

  #pragma unroll 1
  for (int kr = 0; kr < 3; ++kr) {
    half8_t af[6];
    const half8_t* wp = (const half8_t*)(wrep + (size_t)(kr * 64 + ocA) * 192 + q * 8);
    #pragma unroll
    for (int ks = 0; ks < 6; ++ks) af[ks] = wp[ks * 4];
    const int krbase = kr * (16 * 72);
    #pragma unroll
    for (int ks = 0; ks < 6; ++ks) {
      const int k0 = ks * 32 + q * 8;
      const int kadd = krbase + (k0 >> 6) * 72 + (k0 & 63);
      #pragma unroll
      for (int nt = 0; nt < NT; ++nt) {
        half8_t bf = *(const half8_t*)(s_in + base72[nt] + kadd);
        acc[nt] = __builtin_amdgcn_mfma_f32_16x16x32_f16(af[ks], bf, acc[nt], 0, 0, 0);
      }
    }
  }

  const int ocb = wave * 16 + q * 4;
  float scv[4], shv[4];
  #pragma unroll
  for (int rg = 0; rg < 4; ++rg) {
    int o = ocb + rg;
    float s = gam[o] * rsqrtf(var[o] + EPSF);
    scv[rg] = s;
    shv[rg] = (bias[o] - mu[o]) * s + bet[o];
  }
  #pragma unroll
  for (int nt = 0; nt < NT; ++nt) {
    int p = nt * 16 + n16;
    if (p < NPIX) {
      int r = p / OW, c = p - r * OW;
      half4_t v;
      #pragma unroll
      for (int rg = 0; rg < 4; ++rg)
        v[rg] = (_Float16)fmaxf(acc[nt][rg] * scv[rg] + shv[rg], 0.f);
      *(half4_t*)(xout + (((size_t)b * OW + r) * 16 + c) * 64 + ocb) = v;
    }
  }
}

// ---------------------------------------------------------------------------
// K4: conv4 (64->1) + bias + global max. x3h f16 [b][11][16][64].
// ---------------------------------------------------------------------------
__global__ __launch_bounds__(128) void k4_conv4max(
    const _Float16* __restrict__ x3, const float* __restrict__ w4,
    const float* __restrict__ b4, float* __restrict__ out)
{
  __shared__ _Float16 s_in[11 * 16 * 72 + 8];
  __shared__ float s_w[9][64];
  __shared__ float s_red[2];
  const int b = blockIdx.x, t = threadIdx.x;
  {
    const half8_t* src = (const half8_t*)(x3 + (size_t)b * 11 * 16 * 64);
    half8_t* dst = (half8_t*)s_in;
    for (int g = t; g < 11 * 16 * 8; g += 128) {
      int pix = g >> 3, cib = g & 7;
      dst[pix * 9 + cib] = src[g];
    }
  }
  for (int i = t; i < 576; i += 128) {
    int ci = i / 9, k = i - ci * 9;
    s_w[k][ci] = w4[i];
  }
  __syncthreads();
  float val = -INFINITY;
  if (t < 81) {
    const int r = t / 9, c = t - (t / 9) * 9;
    float acc = 0.f;
    #pragma unroll
    for (int kr = 0; kr < 3; ++kr)
      #pragma unroll
      for (int kc = 0; kc < 3; ++kc) {
        const _Float16* ip = s_in + ((r + kr) * 16 + (c + kc)) * 72;
        const float* wk = s_w[kr * 3 + kc];
        #pragma unroll
        for (int cig = 0; cig < 8; ++cig) {
          half8_t x = *(const half8_t*)(ip + cig * 8);
          #pragma unroll
          for (int j = 0; j < 8; ++j)
            acc = fmaf((float)x[j], wk[cig * 8 + j], acc);
        }
      }
    val = acc;
  }
  #pragma unroll
  for (int off = 32; off > 0; off >>= 1)
    val = fmaxf(val, __shfl_down(val, off, 64));
  if ((t & 63) == 0) s_red[t >> 6] = val;
  __syncthreads();
  if (t == 0) out[b] = fmaxf(s_red[0], s_red[1]) + b4[0];
}

// ---------------------------------------------------------------------------
extern "C" void kernel_launch(void* const* d_in, const int* in_sizes, int n_in,
                              void* d_out, int out_size, void* d_ws, size_t ws_size,
                              hipStream_t stream) {
  const float* ts   = (const float*)d_in[0];
  const float* ptm  = (const float*)d_in[1];
  const float* pmt  = (const float*)d_in[2];
  const float* piou = (const float*)d_in[3];
  const int*   mask = (const int*)d_in[4];
  const float* c1w = (const float*)d_in[5];
  const float* c1b = (const float*)d_in[6];
  const float* g1  = (const float*)d_in[7];
  const float* b1  = (const float*)d_in[8];
  const float* m1  = (const float*)d_in[9];
  const float* v1  = (const float*)d_in[10];
  const float* c2w = (const float*)d_in[11];
  const float* c2b = (const float*)d_in[12];
  const float* g2  = (const float*)d_in[13];
  const float* b2  = (const float*)d_in[14];
  const float* m2  = (const float*)d_in[15];
  const float* v2  = (const float*)d_in[16];
  const float* c3w = (const float*)d_in[17];
  const float* c3b = (const float*)d_in[18];
  const float* g3  = (const float*)d_in[19];
  const float* b3  = (const float*)d_in[20];
  const float* m3  = (const float*)d_in[21];
  const float* v3  = (const float*)d_in[22];
  const float* c4w = (const float*)d_in[23];
  const float* c4b = (const float*)d_in[24];

  char* ws = (char*)d_ws;
  _Float16*  img6h  = (_Float16*)ws;
  float*     scal12 = (float*)(ws + OFF_SCAL);
  float*     pmax   = (float*)(ws + OFF_PMAX);
  float2*    wpair  = (float2*)(ws + OFF_WPAIR);
  _Float16*  x1h    = (_Float16*)(ws + OFF_X1H);
  _Float16*  x2h    = (_Float16*)(ws + OFF_X2H);
  _Float16*  x3h    = (_Float16*)(ws + OFF_X3H);
  _Float16*  w2rep  = (_Float16*)(ws + OFF_W2R);
  _Float16*  w3rep  = (_Float16*)(ws + OFF_W3R);
  _Float16*  wr1    = (_Float16*)(ws + OFF_WR1);
  float*     wsum1  = (float*)(ws + OFF_WSUM1);

  k_repack<<<144, 256, 0, stream>>>(c2w, w2rep);
  k_repack<<<144, 256, 0, stream>>>(c3w, w3rep);
  k_repack1<<<26, 256, 0, stream>>>(c1w, wr1, wsum1);
  kA_ptm_max<<<NFB * NMEM / 4, 256, 0, stream>>>(ptm, pmax);
  kB_scal<<<NFB, 256, 0, stream>>>(ts, piou, mask, pmax, scal12, wpair);
  kC_pmt_stats<<<NFB, 256, 0, stream>>>(pmt, wpair, scal12, img6h);
  k1_conv1_mfma<<<NFB, 256, 0, stream>>>(img6h, scal12, wr1, wsum1,
                                         c1b, g1, b1, m1, v1, x1h);
  k_conv_mfma<15, 13, 11><<<NFB, 256, 0, stream>>>(x1h, w2rep, c2b, g2, b2, m2, v2, x2h);
  k_conv_mfma<13, 11, 8><<<NFB, 256, 0, stream>>>(x2h, w3rep, c3b, g3, b3, m3, v3, x3h);
  k4_conv4max<<<NFB, 128, 0, stream>>>(x3h, c4w, c4b, (float*)d_out);
}

// Round 7
// 225.401 us; speedup vs baseline: 5.6555x; 1.1657x over previous
//
#include <hip/hip_runtime.h>
#include <math.h>

#define NFB  512     // B = nf*ns
#define NMEM 30
#define PIX  1024    // 32*32
#define EPSF 1e-5f

typedef _Float16 half8_t __attribute__((ext_vector_type(8)));
typedef _Float16 half4_t __attribute__((ext_vector_type(4)));
typedef float float4_t __attribute__((ext_vector_type(4)));

// workspace layout (byte offsets):
// x2h   (f16, 512*13*16*64)  @ 0           size 13,631,488
// w2rep (f16, 3*64*192)      @ 13,631,488  size 73,728
// w3rep (f16, 3*64*192)      @ 13,705,216  size 73,728
// wr1   (f16, 3*64*32)       @ 13,778,944  size 12,288
// wsum1 (fp32, 64*8)         @ 13,791,232  size 2,048   (end 13,793,280)
#define OFF_W2R   13631488
#define OFF_W3R   13705216
#define OFF_WR1   13778944
#define OFF_WSUM1 13791232

// ---------------------------------------------------------------------------
// k_prep: all weight repacks in one launch.
//  w2rep/w3rep: [oc][ci][3][3] fp32 -> [kr][oc][kc*64+ci] f16
//  wr1: conv1 image-channel weights [kr][oc][kc*8+ci] f16 (zero-padded)
//  wsum1: per-(oc,u) 3x3 tap sums for the 8 uniform channels
// ---------------------------------------------------------------------------
__global__ __launch_bounds__(256) void k_prep(
    const float* __restrict__ c1w, const float* __restrict__ c2w,
    const float* __restrict__ c3w, _Float16* __restrict__ w2rep,
    _Float16* __restrict__ w3rep, _Float16* __restrict__ wr1,
    float* __restrict__ wsum1)
{
  int i = blockIdx.x * 256 + threadIdx.x;
  if (i < 36864) {
    int kr = i / 12288, rem = i - kr * 12288;
    int oc = rem / 192, k = rem - oc * 192;
    int kc = k >> 6, ci = k & 63;
    w2rep[i] = (_Float16)c2w[((oc * 64 + ci) * 3 + kr) * 3 + kc];
  } else if (i < 73728) {
    int j = i - 36864;
    int kr = j / 12288, rem = j - kr * 12288;
    int oc = rem / 192, k = rem - oc * 192;
    int kc = k >> 6, ci = k & 63;
    w3rep[j] = (_Float16)c3w[((oc * 64 + ci) * 3 + kr) * 3 + kc];
  } else if (i < 79872) {
    int j = i - 73728;
    int kr = j / 2048, rem = j - kr * 2048;
    int oc = rem >> 5, k = rem & 31;
    int kc = k >> 3, ci = k & 7;
    _Float16 v = (_Float16)0.f;
    if (kc < 3 && ci < 6)
      v = (_Float16)c1w[((oc * 14 + (2 + ci)) * 3 + kr) * 3 + kc];
    wr1[j] = v;
  } else if (i < 80384) {
    int j = i - 79872;
    int oc = j >> 3, u = j & 7;
    const int uch[8] = {0, 1, 8, 9, 10, 11, 12, 13};
    const float* wp = c1w + (oc * 14 + uch[u]) * 9;
    float s = 0.f;
    #pragma unroll
    for (int k = 0; k < 9; ++k) s += wp[k];
    wsum1[j] = s;
  }
}

// ---------------------------------------------------------------------------
// k_mega: the whole per-b pipeline in one kernel. 512 blocks x 256 threads.
// LDS plan (bytes):
//   IMG [0, 16448)      1028 px * 8 halves   (stats output / conv1 B)
//   X1  [16448, 51008)  240 px * 72 halves   (conv1 out / conv2 B)
//   X2S [0, 29952)      208 px * 72 halves   (restaged x2h / conv3 B; IMG+X1 dead)
//   X3  [29952, 55296)  176 px * 72 halves   (conv3 out / conv4 in)
// ---------------------------------------------------------------------------
__global__ __launch_bounds__(256, 2) void k_mega(
    const float* __restrict__ ts, const float* __restrict__ ptm,
    const float* __restrict__ pmt, const float* __restrict__ piou,
    const int* __restrict__ mask,
    const _Float16* __restrict__ wr1, const float* __restrict__ wsum1,
    const float* __restrict__ c1b, const float* __restrict__ g1,
    const float* __restrict__ b1, const float* __restrict__ m1,
    const float* __restrict__ v1,
    const _Float16* __restrict__ w2rep,
    const float* __restrict__ c2b, const float* __restrict__ g2,
    const float* __restrict__ b2, const float* __restrict__ m2,
    const float* __restrict__ v2,
    const _Float16* __restrict__ w3rep,
    const float* __restrict__ c3b, const float* __restrict__ g3,
    const float* __restrict__ b3, const float* __restrict__ m3,
    const float* __restrict__ v3,
    const float* __restrict__ c4w, const float* __restrict__ c4b,
    _Float16* __restrict__ x2h, float* __restrict__ out)
{
  __shared__ __align__(16) char s_buf[55296];
  __shared__ float s_wm[NMEM], s_wo[NMEM], s_pmax[NMEM];
  __shared__ float s_red[4], s_scal[12], s_cnt[4];
  __shared__ float s_w4[576];   // [k][ci]

  const int b = blockIdx.x, t = threadIdx.x;
  const int lane = t & 63, wave = t >> 6;
  const int n16 = lane & 15, q = lane >> 4;
  _Float16* const IMG = (_Float16*)s_buf;
  _Float16* const X1  = (_Float16*)(s_buf + 16448);
  _Float16* const X2S = (_Float16*)s_buf;
  _Float16* const X3  = (_Float16*)(s_buf + 29952);

  // ======== stage A: stats ========
  // conv4 weights -> LDS (no dependency; hide early)
  for (int i = t; i < 576; i += 256) {
    int ci = i / 9, k = i - ci * 9;
    s_w4[k * 64 + ci] = c4w[i];
  }
  // mask weights + counts (t0)
  if (t == 0) {
    float cum = 0.f, cm = 0.f, cg = 0.f, co = 0.f;
    for (int m = 0; m < NMEM; ++m) {
      float f  = (mask[b * NMEM + m] != 0) ? 1.f : 0.f;
      float gg = (cum < 15.f) ? f : 0.f;
      float oo = f - gg;
      cum += f;
      s_wm[m] = f; s_wo[m] = oo;
      cm += f; cg += gg; co += oo;
    }
    s_cnt[0] = cm; s_cnt[1] = cg; s_cnt[2] = co;
  }
  // per-memory spatial max of ptm (one wave per memory, strided)
  for (int m = wave; m < NMEM; m += 4) {
    const float* p = ptm + ((size_t)b * NMEM + m) * PIX;
    float4 v0 = *(const float4*)(p + lane * 4);
    float4 v1_ = *(const float4*)(p + lane * 4 + 256);
    float4 v2_ = *(const float4*)(p + lane * 4 + 512);
    float4 v3_ = *(const float4*)(p + lane * 4 + 768);
    float mx = fmaxf(fmaxf(fmaxf(v0.x, v0.y), fmaxf(v0.z, v0.w)),
                     fmaxf(fmaxf(v1_.x, v1_.y), fmaxf(v1_.z, v1_.w)));
    mx = fmaxf(mx, fmaxf(fmaxf(fmaxf(v2_.x, v2_.y), fmaxf(v2_.z, v2_.w)),
                         fmaxf(fmaxf(v3_.x, v3_.y), fmaxf(v3_.z, v3_.w))));
    #pragma unroll
    for (int off = 32; off > 0; off >>= 1)
      mx = fmaxf(mx, __shfl_down(mx, off, 64));
    if (lane == 0) s_pmax[m] = mx;
  }
  // ts max
  {
    float4 v = ((const float4*)(ts + (size_t)b * PIX))[t];
    float mx = fmaxf(fmaxf(v.x, v.y), fmaxf(v.z, v.w));
    #pragma unroll
    for (int off = 32; off > 0; off >>= 1)
      mx = fmaxf(mx, __shfl_down(mx, off, 64));
    if (lane == 0) s_red[wave] = mx;
  }
  __syncthreads();
  // scalar stats (t0) — others proceed straight into pmt loop (no s_scal use)
  if (t == 0) {
    float maxts = fmaxf(fmaxf(s_red[0], s_red[1]), fmaxf(s_red[2], s_red[3]));
    float sm = 0, sm2 = 0, sg = 0, sg2 = 0, so = 0, so2 = 0;
    for (int m = 0; m < NMEM; ++m) {
      float x = s_pmax[m];
      float gg = s_wm[m] - s_wo[m];
      sm += s_wm[m] * x;  sm2 += s_wm[m] * x * x;
      sg += gg * x;       sg2 += gg * x * x;
      so += s_wo[m] * x;  so2 += s_wo[m] * x * x;
    }
    float cm = s_cnt[0], cg = s_cnt[1], co = s_cnt[2];
    float a = sm / cm, g = sg / cg, o = so / co;
    s_scal[0] = maxts; s_scal[1] = piou[b];
    s_scal[2] = a; s_scal[3] = sqrtf(fmaxf(sm2 / cm - a * a, 0.f));
    s_scal[4] = g; s_scal[5] = sqrtf(fmaxf(sg2 / cg - g * g, 0.f));
    s_scal[6] = o; s_scal[7] = sqrtf(fmaxf(so2 / co - o * o, 0.f));
  }
  // per-pixel pmt stats -> IMG (each thread owns 4 consecutive pixels)
  {
    const float cm = s_cnt[0], co = s_cnt[2];
    const int p0 = t * 4;
    const float* pb = pmt + (size_t)b * NMEM * PIX + p0;
    float sA[4] = {0,0,0,0}, qA[4] = {0,0,0,0};
    float sG[4] = {0,0,0,0}, qG[4] = {0,0,0,0};
    float sO[4] = {0,0,0,0}, qO[4] = {0,0,0,0};
    #pragma unroll 1
    for (int mb = 0; mb < 15; mb += 5) {
      float4 v[5];
      #pragma unroll
      for (int j = 0; j < 5; ++j) v[j] = *(const float4*)(pb + (size_t)(mb + j) * PIX);
      #pragma unroll
      for (int j = 0; j < 5; ++j) {
        float wm = s_wm[mb + j], wo = s_wo[mb + j];
        float xv[4] = {v[j].x, v[j].y, v[j].z, v[j].w};
        #pragma unroll
        for (int k = 0; k < 4; ++k) {
          float x = xv[k];
          sA[k] = fmaf(wm, x, sA[k]); qA[k] = fmaf(wm * x, x, qA[k]);
          sO[k] = fmaf(wo, x, sO[k]); qO[k] = fmaf(wo * x, x, qO[k]);
          sG[k] += x; qG[k] = fmaf(x, x, qG[k]);
        }
      }
    }
    #pragma unroll 1
    for (int mb = 15; mb < 30; mb += 5) {
      float4 v[5];
      #pragma unroll
      for (int j = 0; j < 5; ++j) v[j] = *(const float4*)(pb + (size_t)(mb + j) * PIX);
      #pragma unroll
      for (int j = 0; j < 5; ++j) {
        float wm = s_wm[mb + j], wo = s_wo[mb + j];
        float xv[4] = {v[j].x, v[j].y, v[j].z, v[j].w};
        #pragma unroll
        for (int k = 0; k < 4; ++k) {
          float x = xv[k];
          sA[k] = fmaf(wm, x, sA[k]); qA[k] = fmaf(wm * x, x, qA[k]);
          sO[k] = fmaf(wo, x, sO[k]); qO[k] = fmaf(wo * x, x, qO[k]);
        }
      }
    }
    half8_t* ob = (half8_t*)(IMG) + p0;
    #pragma unroll
    for (int j = 0; j < 4; ++j) {
      float m0 = sA[j] / cm;   float d0 = sqrtf(fmaxf(qA[j] / cm - m0 * m0, 0.f));
      float m1_ = sG[j] / 15.f; float d1 = sqrtf(fmaxf(qG[j] / 15.f - m1_ * m1_, 0.f));
      float m2_ = sO[j] / co;   float d2 = sqrtf(fmaxf(qO[j] / co - m2_ * m2_, 0.f));
      half8_t v;
      v[0] = (_Float16)m0;  v[1] = (_Float16)d0;
      v[2] = (_Float16)m1_; v[3] = (_Float16)d1;
      v[4] = (_Float16)m2_; v[5] = (_Float16)d2;
      v[6] = (_Float16)0.f; v[7] = (_Float16)0.f;
      ob[j] = v;
    }
    if (t < 4) {   // zero the 4 pad pixels (1024..1027)
      half8_t z = {(_Float16)0.f,(_Float16)0.f,(_Float16)0.f,(_Float16)0.f,
                   (_Float16)0.f,(_Float16)0.f,(_Float16)0.f,(_Float16)0.f};
      ((half8_t*)IMG)[1024 + t] = z;
    }
  }
  __syncthreads();

  // ======== conv1 (MFMA) + BN + ReLU + 2x2 maxpool -> X1 (LDS, stride 72) ====
  {
    const int ocA = wave * 16 + n16;
    half8_t af[3];
    #pragma unroll
    for (int kr = 0; kr < 3; ++kr)
      af[kr] = *(const half8_t*)(wr1 + (kr * 64 + ocA) * 32 + q * 8);
    const int oc0 = wave * 16 + q * 4;
    float scv[4], shv[4], cst[4];
    #pragma unroll
    for (int rg = 0; rg < 4; ++rg) {
      int oc = oc0 + rg;
      float s = g1[oc] * rsqrtf(v1[oc] + EPSF);
      scv[rg] = s;
      shv[rg] = (c1b[oc] - m1[oc]) * s + b1[oc];
      float c = 0.f;
      #pragma unroll
      for (int u = 0; u < 8; ++u) c = fmaf(wsum1[oc * 8 + u], s_scal[u], c);
      cst[rg] = c;
    }
    #pragma unroll 1
    for (int pr = 0; pr < 15; ++pr) {
      const int r0 = pr * 2;
      float4_t acc[2][2];
      #pragma unroll
      for (int row = 0; row < 2; ++row)
        #pragma unroll
        for (int tt = 0; tt < 2; ++tt)
          acc[row][tt] = (float4_t){0.f, 0.f, 0.f, 0.f};
      #pragma unroll
      for (int row = 0; row < 2; ++row) {
        #pragma unroll
        for (int kr = 0; kr < 3; ++kr) {
          const int ip = (r0 + row + kr) * 32 + n16 + q;
          #pragma unroll
          for (int tt = 0; tt < 2; ++tt) {
            half8_t bf = *(const half8_t*)(IMG + (ip + tt * 16) * 8);
            acc[row][tt] = __builtin_amdgcn_mfma_f32_16x16x32_f16(
                af[kr], bf, acc[row][tt], 0, 0, 0);
          }
        }
      }
      #pragma unroll
      for (int tt = 0; tt < 2; ++tt) {
        float mm[4];
        #pragma unroll
        for (int j = 0; j < 4; ++j) {
          float m = fmaxf(acc[0][tt][j], acc[1][tt][j]);
          mm[j] = fmaxf(m, __shfl_xor(m, 1, 64));
        }
        if ((n16 & 1) == 0) {
          int pc = tt * 8 + (n16 >> 1);
          half4_t vv;
          if (pc < 15) {
            #pragma unroll
            for (int rg = 0; rg < 4; ++rg)
              vv[rg] = (_Float16)fmaxf(scv[rg] * (mm[rg] + cst[rg]) + shv[rg], 0.f);
          } else {
            vv[0] = (_Float16)0.f; vv[1] = (_Float16)0.f;
            vv[2] = (_Float16)0.f; vv[3] = (_Float16)0.f;
          }
          *(half4_t*)(X1 + (pr * 16 + pc) * 72 + oc0) = vv;
        }
      }
    }
  }
  __syncthreads();

  // ======== conv2 (MFMA): X1(LDS) -> x2h(global) ========
  {
    int base72[11];
    #pragma unroll
    for (int nt = 0; nt < 11; ++nt) {
      int p = nt * 16 + n16;
      int pe = (p < 169) ? p : 168;
      int r = pe / 13, c = pe - r * 13;
      base72[nt] = (r * 16 + c) * 72;
    }
    float4_t acc[11];
    #pragma unroll
    for (int nt = 0; nt < 11; ++nt) acc[nt] = (float4_t){0.f, 0.f, 0.f, 0.f};
    const int ocA = wave * 16 + n16;
    #pragma unroll 1
    for (int kr = 0; kr < 3; ++kr) {
      half8_t af[6];
      const half8_t* wp = (const half8_t*)(w2rep + (size_t)(kr * 64 + ocA) * 192 + q * 8);
      #pragma unroll
      for (int ks = 0; ks < 6; ++ks) af[ks] = wp[ks * 4];
      const int krbase = kr * (16 * 72);
      #pragma unroll
      for (int ks = 0; ks < 6; ++ks) {
        const int k0 = ks * 32 + q * 8;
        const int kadd = krbase + (k0 >> 6) * 72 + (k0 & 63);
        #pragma unroll
        for (int nt = 0; nt < 11; ++nt) {
          half8_t bf = *(const half8_t*)(X1 + base72[nt] + kadd);
          acc[nt] = __builtin_amdgcn_mfma_f32_16x16x32_f16(af[ks], bf, acc[nt], 0, 0, 0);
        }
      }
    }
    const int ocb = wave * 16 + q * 4;
    float scv[4], shv[4];
    #pragma unroll
    for (int rg = 0; rg < 4; ++rg) {
      int o = ocb + rg;
      float s = g2[o] * rsqrtf(v2[o] + EPSF);
      scv[rg] = s;
      shv[rg] = (c2b[o] - m2[o]) * s + b2[o];
    }
    #pragma unroll
    for (int nt = 0; nt < 11; ++nt) {
      int p = nt * 16 + n16;
      if (p < 169) {
        int r = p / 13, c = p - r * 13;
        half4_t vv;
        #pragma unroll
        for (int rg = 0; rg < 4; ++rg)
          vv[rg] = (_Float16)fmaxf(acc[nt][rg] * scv[rg] + shv[rg], 0.f);
        *(half4_t*)(x2h + (((size_t)b * 13 + r) * 16 + c) * 64 + ocb) = vv;
      }
    }
  }
  __threadfence_block();
  __syncthreads();
  // restage x2h -> X2S (stride 72)
  {
    const half8_t* src = (const half8_t*)(x2h + (size_t)b * 13 * 16 * 64);
    half8_t* dst = (half8_t*)X2S;
    for (int g = t; g < 208 * 8; g += 256) {
      int pix = g >> 3, cib = g & 7;
      dst[pix * 9 + cib] = src[g];
    }
  }
  __syncthreads();

  // ======== conv3 (MFMA): X2S -> X3 (LDS) ========
  {
    int base72[8];
    #pragma unroll
    for (int nt = 0; nt < 8; ++nt) {
      int p = nt * 16 + n16;
      int pe = (p < 121) ? p : 120;
      int r = pe / 11, c = pe - r * 11;
      base72[nt] = (r * 16 + c) * 72;
    }
    float4_t acc[8];
    #pragma unroll
    for (int nt = 0; nt < 8; ++nt) acc[nt] = (float4_t){0.f, 0.f, 0.f, 0.f};
    const int ocA = wave * 16 + n16;
    #pragma unroll 1
    for (int kr = 0; kr < 3; ++kr) {
      half8_t af[6];
      const half8_t* wp = (const half8_t*)(w3rep + (size_t)(kr * 64 + ocA) * 192 + q * 8);
      #pragma unroll
      for (int ks = 0; ks < 6; ++ks) af[ks] = wp[ks * 4];
      const int krbase = kr * (16 * 72);
      #pragma unroll
      for (int ks = 0; ks < 6; ++ks) {
        const int k0 = ks * 32 + q * 8;
        const int kadd = krbase + (k0 >> 6) * 72 + (k0 & 63);
        #pragma unroll
        for (int nt = 0; nt < 8; ++nt) {
          half8_t bf = *(const half8_t*)(X2S + base72[nt] + kadd);
          acc[nt] = __builtin_amdgcn_mfma_f32_16x16x32_f16(af[ks], bf, acc[nt], 0, 0, 0);
        }
      }
    }
    const int ocb = wave * 16 + q * 4;
    float scv[4], shv[4];
    #pragma unroll
    for (int rg = 0; rg < 4; ++rg) {
      int o = ocb + rg;
      float s = g3[o] * rsqrtf(v3[o] + EPSF);
      scv[rg] = s;
      shv[rg] = (c3b[o] - m3[o]) * s + b3[o];
    }
    #pragma unroll
    for (int nt = 0; nt < 8; ++nt) {
      int p = nt * 16 + n16;
      if (p < 121) {
        int r = p / 11, c = p - r * 11;
        half4_t vv;
        #pragma unroll
        for (int rg = 0; rg < 4; ++rg)
          vv[rg] = (_Float16)fmaxf(acc[nt][rg] * scv[rg] + shv[rg], 0.f);
        *(half4_t*)(X3 + (r * 16 + c) * 72 + ocb) = vv;
      }
    }
  }
  __syncthreads();

  // ======== conv4 (64->1) + bias + global max -> out[b] ========
  {
    float val = -INFINITY;
    if (t < 81) {
      const int r = t / 9, c = t - (t / 9) * 9;
      float acc = 0.f;
      #pragma unroll
      for (int kr = 0; kr < 3; ++kr)
        #pragma unroll
        for (int kc = 0; kc < 3; ++kc) {
          const _Float16* ip = X3 + ((r + kr) * 16 + (c + kc)) * 72;
          const float* wk = s_w4 + (kr * 3 + kc) * 64;
          #pragma unroll
          for (int cig = 0; cig < 8; ++cig) {
            half8_t x = *(const half8_t*)(ip + cig * 8);
            #pragma unroll
            for (int j = 0; j < 8; ++j)
              acc = fmaf((float)x[j], wk[cig * 8 + j], acc);
          }
        }
      val = acc;
    }
    #pragma unroll
    for (int off = 32; off > 0; off >>= 1)
      val = fmaxf(val, __shfl_down(val, off, 64));
    if (lane == 0) s_red[wave] = val;
    __syncthreads();
    if (t == 0)
      out[b] = fmaxf(fmaxf(s_red[0], s_red[1]), fmaxf(s_red[2], s_red[3])) + c4b[0];
  }
}

// ---------------------------------------------------------------------------
extern "C" void kernel_launch(void* const* d_in, const int* in_sizes, int n_in,
                              void* d_out, int out_size, void* d_ws, size_t ws_size,
                              hipStream_t stream) {
  const float* ts   = (const float*)d_in[0];
  const float* ptm  = (const float*)d_in[1];
  const float* pmt  = (const float*)d_in[2];
  const float* piou = (const float*)d_in[3];
  const int*   mask = (const int*)d_in[4];
  const float* c1w = (const float*)d_in[5];
  const float* c1b = (const float*)d_in[6];
  const float* g1  = (const float*)d_in[7];
  const float* b1  = (const float*)d_in[8];
  const float* m1  = (const float*)d_in[9];
  const float* v1  = (const float*)d_in[10];
  const float* c2w = (const float*)d_in[11];
  const float* c2b = (const float*)d_in[12];
  const float* g2  = (const float*)d_in[13];
  const float* b2  = (const float*)d_in[14];
  const float* m2  = (const float*)d_in[15];
  const float* v2  = (const float*)d_in[16];
  const float* c3w = (const float*)d_in[17];
  const float* c3b = (const float*)d_in[18];
  const float* g3  = (const float*)d_in[19];
  const float* b3  = (const float*)d_in[20];
  const float* m3  = (const float*)d_in[21];
  const float* v3  = (const float*)d_in[22];
  const float* c4w = (const float*)d_in[23];
  const float* c4b = (const float*)d_in[24];

  char* ws = (char*)d_ws;
  _Float16*  x2h   = (_Float16*)ws;
  _Float16*  w2rep = (_Float16*)(ws + OFF_W2R);
  _Float16*  w3rep = (_Float16*)(ws + OFF_W3R);
  _Float16*  wr1   = (_Float16*)(ws + OFF_WR1);
  float*     wsum1 = (float*)(ws + OFF_WSUM1);

  k_prep<<<314, 256, 0, stream>>>(c1w, c2w, c3w, w2rep, w3rep, wr1, wsum1);
  k_mega<<<NFB, 256, 0, stream>>>(
      ts, ptm, pmt, piou, mask,
      wr1, wsum1, c1b, g1, b1, m1, v1,
      w2rep, c2b, g2, b2, m2, v2,
      w3rep, c3b, g3, b3, m3, v3,
      c4w, c4b, x2h, (float*)d_out);
}